// Round 1
// baseline (370.460 us; speedup 1.0000x reference)
//
#include <hip/hip_runtime.h>
#include <cstdint>

// ---------------------------------------------------------------------------
// LoRA MHA: B=4,S=1024,E=1024,H=16,D=64,R=16.  All GEMMs as bf16 MFMA with
// fp32 accum.  LoRA folded into K-augmented GEMM: K = 1024 + 64 = 1088.
// Slots in the augmented 64 cols: [q:0-15][k:16-31][v:32-47][o:48-63].
// ---------------------------------------------------------------------------

#define KAUG 1088
#define M_ROWS 4096

typedef __attribute__((ext_vector_type(8))) short bf16x8;
typedef __attribute__((ext_vector_type(4))) float f32x4;
typedef __attribute__((ext_vector_type(4))) unsigned short u16x4;

__device__ __forceinline__ short f2bf(float f) {
  unsigned u = __builtin_bit_cast(unsigned, f);
  u += 0x7FFFu + ((u >> 16) & 1u);          // RNE
  return (short)(u >> 16);
}
__device__ __forceinline__ float bf2f(unsigned short s) {
  return __builtin_bit_cast(float, (unsigned)s << 16);
}

typedef __attribute__((address_space(1))) const unsigned int as1_uint;
typedef __attribute__((address_space(3))) unsigned int as3_uint;

// global -> LDS direct copy, 16B per lane.  LDS base must be wave-uniform;
// HW writes lane*16.  (guide §5; CK-style uintptr truncation for AS3.)
__device__ __forceinline__ void gload_lds16(const short* g, const short* l) {
  __builtin_amdgcn_global_load_lds((as1_uint*)g,
      (as3_uint*)(unsigned int)(uintptr_t)l, 16, 0, 0);
}

// ---------------------------------------------------------------------------
// Kernel 1: cast x (fp32) into Xaug cols 0..1023 (bf16), row stride 1088.
// ---------------------------------------------------------------------------
__global__ void build_x(const float* __restrict__ x, short* __restrict__ xa) {
  int idx = blockIdx.x * 256 + threadIdx.x;       // over 4096*256 float4 groups
  int row = idx >> 8;
  int c = (idx & 255) * 4;
  f32x4 v = ((const f32x4*)x)[idx];
  u16x4 o;
  o[0] = (unsigned short)f2bf(v[0]);
  o[1] = (unsigned short)f2bf(v[1]);
  o[2] = (unsigned short)f2bf(v[2]);
  o[3] = (unsigned short)f2bf(v[3]);
  *(u16x4*)(xa + (size_t)row * KAUG + c) = o;
}

// ---------------------------------------------------------------------------
// Kernel 2: low_qkv -> Xaug cols 1024..1087.  cols 1024+c: c<48 -> dot of
// x row with A_{q,k,v}[c&15]; c>=48 -> 0 (pad, o-slot filled later).
// ---------------------------------------------------------------------------
__global__ void low_qkv(const float* __restrict__ x, const float* __restrict__ aq,
                        const float* __restrict__ ak, const float* __restrict__ av,
                        short* __restrict__ xa) {
  int m = blockIdx.x * 4 + (threadIdx.x >> 6);
  int c = threadIdx.x & 63;
  float acc = 0.f;
  if (c < 48) {
    const float* A = (c < 16 ? aq : (c < 32 ? ak : av)) + (size_t)(c & 15) * 1024;
    const f32x4* xr = (const f32x4*)(x + (size_t)m * 1024);
    const f32x4* ar = (const f32x4*)A;
    #pragma unroll 4
    for (int i = 0; i < 256; ++i) {
      f32x4 xv = xr[i], a4 = ar[i];
      acc += xv[0] * a4[0] + xv[1] * a4[1] + xv[2] * a4[2] + xv[3] * a4[3];
    }
  }
  xa[(size_t)m * KAUG + 1024 + c] = (c < 48) ? f2bf(acc) : (short)0;
}

// ---------------------------------------------------------------------------
// Kernel 3: build Waug[p][1024][1088]: cols<1024 = W_p, col 1024+j = B_p if
// j in p's 16-slot else 0.
// ---------------------------------------------------------------------------
__global__ void build_waug(const float* __restrict__ wq, const float* __restrict__ wk,
                           const float* __restrict__ wv, const float* __restrict__ wo,
                           const float* __restrict__ lbq, const float* __restrict__ lbk,
                           const float* __restrict__ lbv, const float* __restrict__ lbo,
                           short* __restrict__ wa) {
  int idx = blockIdx.x * 256 + threadIdx.x;       // over 4*1024*272 col4-groups
  int p = idx / (1024 * 272);
  int rem = idx - p * (1024 * 272);
  int n = rem / 272;
  int c4 = rem - n * 272;
  const float* W = (p == 0) ? wq : (p == 1) ? wk : (p == 2) ? wv : wo;
  const float* Bm = (p == 0) ? lbq : (p == 1) ? lbk : (p == 2) ? lbv : lbo;
  u16x4 o;
  if (c4 < 256) {
    f32x4 v = ((const f32x4*)(W + (size_t)n * 1024))[c4];
    o[0] = (unsigned short)f2bf(v[0]);
    o[1] = (unsigned short)f2bf(v[1]);
    o[2] = (unsigned short)f2bf(v[2]);
    o[3] = (unsigned short)f2bf(v[3]);
  } else {
    #pragma unroll
    for (int j = 0; j < 4; ++j) {
      int c = c4 * 4 + j - 1024;                  // 0..63
      o[j] = (unsigned short)(((c >> 4) == p) ? f2bf(Bm[n * 16 + (c & 15)]) : (short)0);
    }
  }
  *(u16x4*)(wa + (size_t)idx * 4) = o;
}

// ---------------------------------------------------------------------------
// GEMM core: 128x128 tile, BK=64, 4 waves (each 64x64 = 4x4 16x16 frags).
// global_load_lds staging with XOR swizzle (slot ^= row&7) to kill the
// 16-way ds_read_b128 bank conflict (guide G4 / rule #21).
// ---------------------------------------------------------------------------
__device__ __forceinline__ void gemm_core(const short* __restrict__ xrow,
                                          const short* __restrict__ wrow,
                                          short* As, short* Bs,
                                          f32x4 (&acc)[4][4]) {
  const int tid = threadIdx.x;
  const int wv = tid >> 6, lane = tid & 63;
  const int wr = wv >> 1, wc = wv & 1;
  const int lrow = lane & 15, lk = lane >> 4;
  const int srow = lane >> 3, sphys = lane & 7;

  for (int kt = 0; kt < 17; ++kt) {
    #pragma unroll
    for (int i = 0; i < 4; ++i) {
      const int ch = i * 4 + wv;                  // 16 chunks of 8 rows
      const int row = ch * 8 + srow;
      const int sl = sphys ^ (row & 7);           // inverse-swizzled source
      gload_lds16(xrow + (size_t)row * KAUG + kt * 64 + sl * 8, As + ch * 512);
      gload_lds16(wrow + (size_t)row * KAUG + kt * 64 + sl * 8, Bs + ch * 512);
    }
    __syncthreads();
    #pragma unroll
    for (int kc = 0; kc < 2; ++kc) {
      bf16x8 af[4], bw[4];
      #pragma unroll
      for (int mi = 0; mi < 4; ++mi) {
        const int row = wr * 64 + mi * 16 + lrow;
        const int slot = (kc * 4 + lk) ^ (row & 7);
        af[mi] = *(const bf16x8*)(As + row * 64 + slot * 8);
      }
      #pragma unroll
      for (int nj = 0; nj < 4; ++nj) {
        const int row = wc * 64 + nj * 16 + lrow;
        const int slot = (kc * 4 + lk) ^ (row & 7);
        bw[nj] = *(const bf16x8*)(Bs + row * 64 + slot * 8);
      }
      #pragma unroll
      for (int mi = 0; mi < 4; ++mi)
        #pragma unroll
        for (int nj = 0; nj < 4; ++nj)
          acc[mi][nj] = __builtin_amdgcn_mfma_f32_16x16x32_bf16(af[mi], bw[nj], acc[mi][nj], 0, 0, 0);
    }
    __syncthreads();
  }
}

// ---------------------------------------------------------------------------
// Kernel 4: fused q/k/v projection (blockIdx.z = projection).
// q,k -> [bh][s][d] bf16 ; v -> transposed [bh][d][s] bf16 (feeds PV B-frag).
// ---------------------------------------------------------------------------
__global__ __launch_bounds__(256)
void gemm_qkv(const short* __restrict__ xa, const short* __restrict__ wa,
              const float* __restrict__ biasq, const float* __restrict__ biask,
              const float* __restrict__ biasv,
              short* __restrict__ qbuf, short* __restrict__ kbuf, short* __restrict__ vtb) {
  __shared__ short As[128 * 64];
  __shared__ short Bs[128 * 64];
  const int p = blockIdx.z;
  const int brow = blockIdx.y, bcol = blockIdx.x;
  const f32x4 fz = {0.f, 0.f, 0.f, 0.f};
  f32x4 acc[4][4];
  #pragma unroll
  for (int a = 0; a < 4; ++a)
    #pragma unroll
    for (int b = 0; b < 4; ++b) acc[a][b] = fz;

  gemm_core(xa + (size_t)brow * 128 * KAUG,
            wa + ((size_t)p * 1024 + (size_t)bcol * 128) * KAUG, As, Bs, acc);

  const int tid = threadIdx.x;
  const int wv = tid >> 6, lane = tid & 63;
  const int wr = wv >> 1, wc = wv & 1;
  const int lrow = lane & 15, lk = lane >> 4;
  const float* bias = (p == 0) ? biasq : (p == 1) ? biask : biasv;
  float bcv[4];
  #pragma unroll
  for (int nj = 0; nj < 4; ++nj)
    bcv[nj] = bias[bcol * 128 + wc * 64 + nj * 16 + lrow];

  #pragma unroll
  for (int mi = 0; mi < 4; ++mi) {
    #pragma unroll
    for (int r = 0; r < 4; ++r) {
      const int gr = brow * 128 + wr * 64 + mi * 16 + lk * 4 + r;   // C/D row
      const int bb = gr >> 10, s = gr & 1023;
      #pragma unroll
      for (int nj = 0; nj < 4; ++nj) {
        const int gc = bcol * 128 + wc * 64 + nj * 16 + lrow;       // C/D col
        const float v = acc[mi][nj][r] + bcv[nj];
        const int h = gc >> 6, d = gc & 63;
        const int bh = bb * 16 + h;
        if (p == 2)
          vtb[((size_t)bh * 64 + d) * 1024 + s] = f2bf(v);
        else
          ((p == 0) ? qbuf : kbuf)[((size_t)bh * 1024 + s) * 64 + d] = f2bf(v);
      }
    }
  }
}

// ---------------------------------------------------------------------------
// Kernel 5: flash attention.  Block = 4 waves, each wave owns 32 q-rows.
// K/V fragments read straight from global (L2-resident: 128KB per bh).
// P goes through a per-wave padded LDS tile to reach MFMA-A layout.
// ctx written (bf16) into Xaug cols 0..1023 (stride 1088) for the o-GEMM.
// ---------------------------------------------------------------------------
__global__ __launch_bounds__(256)
void attn_kernel(const short* __restrict__ qbuf, const short* __restrict__ kbuf,
                 const short* __restrict__ vtb, short* __restrict__ xa) {
  __shared__ short Pl[4][32 * 72];                  // stride 72 (16B-aligned, padded)
  const int qt = blockIdx.x, bh = blockIdx.y;
  const int tid = threadIdx.x, w = tid >> 6, lane = tid & 63;
  const int lrow = lane & 15, lk = lane >> 4;
  const short* Qp = qbuf + (size_t)bh * 65536;
  const short* Kp = kbuf + (size_t)bh * 65536;
  const short* Vp = vtb + (size_t)bh * 65536;
  const int q0 = qt * 128 + w * 32;
  short* pw = &Pl[w][0];

  bf16x8 aq[2][2];
  #pragma unroll
  for (int mi = 0; mi < 2; ++mi)
    #pragma unroll
    for (int kc = 0; kc < 2; ++kc)
      aq[mi][kc] = *(const bf16x8*)(Qp + (size_t)(q0 + mi * 16 + lrow) * 64 + kc * 32 + lk * 8);

  const f32x4 fz = {0.f, 0.f, 0.f, 0.f};
  float m_run[2][4], l_run[2][4];
  f32x4 acc_o[2][4];
  #pragma unroll
  for (int mi = 0; mi < 2; ++mi)
    #pragma unroll
    for (int j = 0; j < 4; ++j) {
      m_run[mi][j] = -1e30f;
      l_run[mi][j] = 0.f;
      acc_o[mi][j] = fz;
    }

  for (int tt = 0; tt < 16; ++tt) {
    const int t0 = tt * 64;
    bf16x8 bkf[4][2];
    #pragma unroll
    for (int nj = 0; nj < 4; ++nj)
      #pragma unroll
      for (int kc = 0; kc < 2; ++kc)
        bkf[nj][kc] = *(const bf16x8*)(Kp + (size_t)(t0 + nj * 16 + lrow) * 64 + kc * 32 + lk * 8);

    f32x4 sacc[2][4];
    #pragma unroll
    for (int mi = 0; mi < 2; ++mi)
      #pragma unroll
      for (int nj = 0; nj < 4; ++nj) sacc[mi][nj] = fz;
    #pragma unroll
    for (int kc = 0; kc < 2; ++kc)
      #pragma unroll
      for (int mi = 0; mi < 2; ++mi)
        #pragma unroll
        for (int nj = 0; nj < 4; ++nj)
          sacc[mi][nj] = __builtin_amdgcn_mfma_f32_16x16x32_bf16(aq[mi][kc], bkf[nj][kc], sacc[mi][nj], 0, 0, 0);

    #pragma unroll
    for (int mi = 0; mi < 2; ++mi)
      #pragma unroll
      for (int nj = 0; nj < 4; ++nj) sacc[mi][nj] *= 0.125f;   // 1/sqrt(64)

    #pragma unroll
    for (int mi = 0; mi < 2; ++mi) {
      #pragma unroll
      for (int r = 0; r < 4; ++r) {
        float tm = fmaxf(fmaxf(sacc[mi][0][r], sacc[mi][1][r]),
                         fmaxf(sacc[mi][2][r], sacc[mi][3][r]));
        tm = fmaxf(tm, __shfl_xor(tm, 1, 64));
        tm = fmaxf(tm, __shfl_xor(tm, 2, 64));
        tm = fmaxf(tm, __shfl_xor(tm, 4, 64));
        tm = fmaxf(tm, __shfl_xor(tm, 8, 64));
        const float mo = m_run[mi][r];
        const float mn = fmaxf(mo, tm);
        const float alpha = __expf(mo - mn);
        m_run[mi][r] = mn;
        float rs = 0.f;
        #pragma unroll
        for (int nj = 0; nj < 4; ++nj) {
          const float pv = __expf(sacc[mi][nj][r] - mn);
          sacc[mi][nj][r] = pv;
          rs += pv;
        }
        rs += __shfl_xor(rs, 1, 64);
        rs += __shfl_xor(rs, 2, 64);
        rs += __shfl_xor(rs, 4, 64);
        rs += __shfl_xor(rs, 8, 64);
        l_run[mi][r] = l_run[mi][r] * alpha + rs;
        #pragma unroll
        for (int dn = 0; dn < 4; ++dn) acc_o[mi][dn][r] *= alpha;
      }
    }

    // P (C/D layout) -> LDS -> re-read in MFMA-A layout (wave-local, no barrier)
    #pragma unroll
    for (int mi = 0; mi < 2; ++mi)
      #pragma unroll
      for (int r = 0; r < 4; ++r)
        #pragma unroll
        for (int nj = 0; nj < 4; ++nj)
          pw[(mi * 16 + lk * 4 + r) * 72 + nj * 16 + lrow] = f2bf(sacc[mi][nj][r]);

    #pragma unroll
    for (int kc = 0; kc < 2; ++kc) {
      bf16x8 pa[2];
      #pragma unroll
      for (int mi = 0; mi < 2; ++mi)
        pa[mi] = *(const bf16x8*)(pw + (mi * 16 + lrow) * 72 + kc * 32 + lk * 8);
      #pragma unroll
      for (int dn = 0; dn < 4; ++dn) {
        const bf16x8 bv8 = *(const bf16x8*)(Vp + (size_t)(dn * 16 + lrow) * 1024 + t0 + kc * 32 + lk * 8);
        #pragma unroll
        for (int mi = 0; mi < 2; ++mi)
          acc_o[mi][dn] = __builtin_amdgcn_mfma_f32_16x16x32_bf16(pa[mi], bv8, acc_o[mi][dn], 0, 0, 0);
      }
    }
  }

  const int bb = bh >> 4, h = bh & 15;
  #pragma unroll
  for (int mi = 0; mi < 2; ++mi) {
    #pragma unroll
    for (int r = 0; r < 4; ++r) {
      const float inv = 1.f / l_run[mi][r];
      const int s = q0 + mi * 16 + lk * 4 + r;
      const size_t gr = (size_t)(bb * 1024 + s) * KAUG;
      #pragma unroll
      for (int dn = 0; dn < 4; ++dn) {
        const int col = h * 64 + dn * 16 + lrow;
        xa[gr + col] = f2bf(acc_o[mi][dn][r] * inv);
      }
    }
  }
}

// ---------------------------------------------------------------------------
// Kernel 6: o-LoRA low: Xaug cols 1024..1087: c>=48 -> dot(ctx_row, A_o[c-48]),
// c<48 -> 0.  Reads ctx (cols<1024) / writes cols>=1024 of the same buffer.
// ---------------------------------------------------------------------------
__global__ void low_o(const short* __restrict__ xr_ctx, const float* __restrict__ ao,
                      short* __restrict__ xa) {
  int m = blockIdx.x * 4 + (threadIdx.x >> 6);
  int c = threadIdx.x & 63;
  float acc = 0.f;
  if (c >= 48) {
    const float* A = ao + (size_t)(c - 48) * 1024;
    const u16x4* xr = (const u16x4*)(xr_ctx + (size_t)m * KAUG);
    const f32x4* ar = (const f32x4*)A;
    #pragma unroll 4
    for (int i = 0; i < 256; ++i) {
      u16x4 xv = xr[i];
      f32x4 a4 = ar[i];
      acc += bf2f(xv[0]) * a4[0] + bf2f(xv[1]) * a4[1] + bf2f(xv[2]) * a4[2] + bf2f(xv[3]) * a4[3];
    }
  }
  xa[(size_t)m * KAUG + 1024 + c] = (c >= 48) ? f2bf(acc) : (short)0;
}

// ---------------------------------------------------------------------------
// Kernel 7: o-projection -> fp32 d_out.
// ---------------------------------------------------------------------------
__global__ __launch_bounds__(256)
void gemm_o(const short* __restrict__ xa, const short* __restrict__ wa,
            const float* __restrict__ biaso, float* __restrict__ out) {
  __shared__ short As[128 * 64];
  __shared__ short Bs[128 * 64];
  const int brow = blockIdx.y, bcol = blockIdx.x;
  const f32x4 fz = {0.f, 0.f, 0.f, 0.f};
  f32x4 acc[4][4];
  #pragma unroll
  for (int a = 0; a < 4; ++a)
    #pragma unroll
    for (int b = 0; b < 4; ++b) acc[a][b] = fz;

  gemm_core(xa + (size_t)brow * 128 * KAUG, wa + (size_t)bcol * 128 * KAUG, As, Bs, acc);

  const int tid = threadIdx.x;
  const int wv = tid >> 6, lane = tid & 63;
  const int wr = wv >> 1, wc = wv & 1;
  const int lrow = lane & 15, lk = lane >> 4;
  float bcv[4];
  #pragma unroll
  for (int nj = 0; nj < 4; ++nj)
    bcv[nj] = biaso[bcol * 128 + wc * 64 + nj * 16 + lrow];

  #pragma unroll
  for (int mi = 0; mi < 4; ++mi) {
    #pragma unroll
    for (int r = 0; r < 4; ++r) {
      const int gr = brow * 128 + wr * 64 + mi * 16 + lk * 4 + r;
      #pragma unroll
      for (int nj = 0; nj < 4; ++nj) {
        const int gc = bcol * 128 + wc * 64 + nj * 16 + lrow;
        out[(size_t)gr * 1024 + gc] = acc[mi][nj][r] + bcv[nj];
      }
    }
  }
}

// ---------------------------------------------------------------------------
extern "C" void kernel_launch(void* const* d_in, const int* in_sizes, int n_in,
                              void* d_out, int out_size, void* d_ws, size_t ws_size,
                              hipStream_t stream) {
  (void)in_sizes; (void)n_in; (void)out_size; (void)ws_size;
  const float* x   = (const float*)d_in[0];
  const float* qw  = (const float*)d_in[1];
  const float* qb  = (const float*)d_in[2];
  const float* qla = (const float*)d_in[3];
  const float* qlb = (const float*)d_in[4];
  const float* kw  = (const float*)d_in[5];
  const float* kb  = (const float*)d_in[6];
  const float* kla = (const float*)d_in[7];
  const float* klb = (const float*)d_in[8];
  const float* vw  = (const float*)d_in[9];
  const float* vb  = (const float*)d_in[10];
  const float* vla = (const float*)d_in[11];
  const float* vlb = (const float*)d_in[12];
  const float* ow  = (const float*)d_in[13];
  const float* ob  = (const float*)d_in[14];
  const float* ola = (const float*)d_in[15];
  const float* olb = (const float*)d_in[16];

  short* xaug = (short*)d_ws;                         // 4096*1088
  short* waug = xaug + (size_t)4096 * KAUG;           // 4*1024*1088
  short* qbuf = waug + (size_t)4096 * KAUG;           // 64*1024*64
  short* kbuf = qbuf + (size_t)4194304;
  short* vtb  = kbuf + (size_t)4194304;               // total ~43 MB

  build_x<<<4096, 256, 0, stream>>>(x, xaug);
  low_qkv<<<1024, 256, 0, stream>>>(x, qla, kla, vla, xaug);
  build_waug<<<4352, 256, 0, stream>>>(qw, kw, vw, ow, qlb, klb, vlb, olb, waug);
  gemm_qkv<<<dim3(8, 32, 3), 256, 0, stream>>>(xaug, waug, qb, kb, vb, qbuf, kbuf, vtb);
  attn_kernel<<<dim3(8, 64), 256, 0, stream>>>(qbuf, kbuf, vtb, xaug);
  low_o<<<1024, 256, 0, stream>>>(xaug, ola, xaug);
  gemm_o<<<dim3(8, 32), 256, 0, stream>>>(xaug, waug + (size_t)3 * 1024 * KAUG, ob, (float*)d_out);
}

// Round 2
// 183.175 us; speedup vs baseline: 2.0224x; 2.0224x over previous
//
#include <hip/hip_runtime.h>
#include <cstdint>

// ---------------------------------------------------------------------------
// LoRA MHA: B=4,S=1024,E=1024,H=16,D=64,R=16.  bf16 MFMA, fp32 accum.
// LoRA folded into the weights: W' = W + B@A (scale=1), so every projection
// is a plain K=1024 GEMM.  No separate low-rank pass.
// ---------------------------------------------------------------------------

typedef __attribute__((ext_vector_type(8))) short bf16x8;
typedef __attribute__((ext_vector_type(4))) float f32x4;
typedef __attribute__((ext_vector_type(4))) unsigned short u16x4;

__device__ __forceinline__ short f2bf(float f) {
  unsigned u = __builtin_bit_cast(unsigned, f);
  u += 0x7FFFu + ((u >> 16) & 1u);          // RNE
  return (short)(u >> 16);
}

typedef __attribute__((address_space(1))) const unsigned int as1_uint;
typedef __attribute__((address_space(3))) unsigned int as3_uint;

__device__ __forceinline__ void gload_lds16(const short* g, const short* l) {
  __builtin_amdgcn_global_load_lds((as1_uint*)g,
      (as3_uint*)(unsigned int)(uintptr_t)l, 16, 0, 0);
}

// ---------------------------------------------------------------------------
// Kernel 1: cast x (fp32) -> bf16 [4096][1024].
// ---------------------------------------------------------------------------
__global__ void build_x(const float* __restrict__ x, short* __restrict__ xb) {
  int idx = blockIdx.x * 256 + threadIdx.x;       // over 4096*256 float4 groups
  f32x4 v = ((const f32x4*)x)[idx];
  u16x4 o;
  o[0] = (unsigned short)f2bf(v[0]);
  o[1] = (unsigned short)f2bf(v[1]);
  o[2] = (unsigned short)f2bf(v[2]);
  o[3] = (unsigned short)f2bf(v[3]);
  ((u16x4*)xb)[idx] = o;
}

// ---------------------------------------------------------------------------
// Kernel 2: fold LoRA into weights: W'[p][n][e] = W_p[n][e] + sum_r B_p[n][r]*A_p[r][e]
// fp32 math, bf16 output.  blockIdx.y = projection p.
// ---------------------------------------------------------------------------
__global__ void fold_w(const float* __restrict__ wq, const float* __restrict__ wk,
                       const float* __restrict__ wv, const float* __restrict__ wo,
                       const float* __restrict__ bq, const float* __restrict__ bk,
                       const float* __restrict__ bv, const float* __restrict__ bo,
                       const float* __restrict__ aq, const float* __restrict__ ak,
                       const float* __restrict__ av, const float* __restrict__ ao,
                       short* __restrict__ out) {
  const int p = blockIdx.y;
  const float* W  = (p == 0) ? wq : (p == 1) ? wk : (p == 2) ? wv : wo;
  const float* Bm = (p == 0) ? bq : (p == 1) ? bk : (p == 2) ? bv : bo;
  const float* A  = (p == 0) ? aq : (p == 1) ? ak : (p == 2) ? av : ao;
  const int idx = blockIdx.x * 256 + threadIdx.x;   // over 1024*256 e4-groups
  const int n = idx >> 8;
  const int e4 = idx & 255;
  f32x4 acc = ((const f32x4*)(W + (size_t)n * 1024))[e4];
  const float* br = Bm + n * 16;
  #pragma unroll
  for (int r = 0; r < 16; ++r) {
    const f32x4 a4 = ((const f32x4*)(A + (size_t)r * 1024))[e4];
    const float b = br[r];
    acc[0] += b * a4[0];
    acc[1] += b * a4[1];
    acc[2] += b * a4[2];
    acc[3] += b * a4[3];
  }
  u16x4 o;
  o[0] = (unsigned short)f2bf(acc[0]);
  o[1] = (unsigned short)f2bf(acc[1]);
  o[2] = (unsigned short)f2bf(acc[2]);
  o[3] = (unsigned short)f2bf(acc[3]);
  *(u16x4*)(out + (size_t)p * 1048576 + (size_t)idx * 4) = o;
}

// ---------------------------------------------------------------------------
// GEMM core: 128x128 tile, K=1024, BK=64, 4 waves (each 64x64 = 4x4 frags).
// global_load_lds staging with XOR swizzle (slot ^= row&7), guide G4/rule 21.
// ---------------------------------------------------------------------------
__device__ __forceinline__ void gemm_core(const short* __restrict__ xrow,
                                          const short* __restrict__ wrow,
                                          short* As, short* Bs,
                                          f32x4 (&acc)[4][4]) {
  const int tid = threadIdx.x;
  const int wv = tid >> 6, lane = tid & 63;
  const int wr = wv >> 1, wc = wv & 1;
  const int lrow = lane & 15, lk = lane >> 4;
  const int srow = lane >> 3, sphys = lane & 7;

  for (int kt = 0; kt < 16; ++kt) {
    #pragma unroll
    for (int i = 0; i < 4; ++i) {
      const int ch = i * 4 + wv;                  // 16 chunks of 8 rows
      const int row = ch * 8 + srow;
      const int sl = sphys ^ (row & 7);           // inverse-swizzled source
      gload_lds16(xrow + (size_t)row * 1024 + kt * 64 + sl * 8, As + ch * 512);
      gload_lds16(wrow + (size_t)row * 1024 + kt * 64 + sl * 8, Bs + ch * 512);
    }
    __syncthreads();
    #pragma unroll
    for (int kc = 0; kc < 2; ++kc) {
      bf16x8 af[4], bw[4];
      #pragma unroll
      for (int mi = 0; mi < 4; ++mi) {
        const int row = wr * 64 + mi * 16 + lrow;
        const int slot = (kc * 4 + lk) ^ (row & 7);
        af[mi] = *(const bf16x8*)(As + row * 64 + slot * 8);
      }
      #pragma unroll
      for (int nj = 0; nj < 4; ++nj) {
        const int row = wc * 64 + nj * 16 + lrow;
        const int slot = (kc * 4 + lk) ^ (row & 7);
        bw[nj] = *(const bf16x8*)(Bs + row * 64 + slot * 8);
      }
      #pragma unroll
      for (int mi = 0; mi < 4; ++mi)
        #pragma unroll
        for (int nj = 0; nj < 4; ++nj)
          acc[mi][nj] = __builtin_amdgcn_mfma_f32_16x16x32_bf16(af[mi], bw[nj], acc[mi][nj], 0, 0, 0);
    }
    __syncthreads();
  }
}

// ---------------------------------------------------------------------------
// Kernel 3: fused q/k/v projection (blockIdx.z = projection).
// q,k -> [bh][s][d] bf16 ; v -> transposed [bh][d][s] bf16 (feeds PV B-frag).
// ---------------------------------------------------------------------------
__global__ __launch_bounds__(256)
void gemm_qkv(const short* __restrict__ xb, const short* __restrict__ wb,
              const float* __restrict__ biasq, const float* __restrict__ biask,
              const float* __restrict__ biasv,
              short* __restrict__ qbuf, short* __restrict__ kbuf, short* __restrict__ vtb) {
  __shared__ short As[128 * 64];
  __shared__ short Bs[128 * 64];
  const int p = blockIdx.z;
  const int brow = blockIdx.y, bcol = blockIdx.x;
  const f32x4 fz = {0.f, 0.f, 0.f, 0.f};
  f32x4 acc[4][4];
  #pragma unroll
  for (int a = 0; a < 4; ++a)
    #pragma unroll
    for (int b = 0; b < 4; ++b) acc[a][b] = fz;

  gemm_core(xb + (size_t)brow * 128 * 1024,
            wb + ((size_t)p * 1024 + (size_t)bcol * 128) * 1024, As, Bs, acc);

  const int tid = threadIdx.x;
  const int wv = tid >> 6, lane = tid & 63;
  const int wr = wv >> 1, wc = wv & 1;
  const int lrow = lane & 15, lk = lane >> 4;
  const float* bias = (p == 0) ? biasq : (p == 1) ? biask : biasv;
  float bcv[4];
  #pragma unroll
  for (int nj = 0; nj < 4; ++nj)
    bcv[nj] = bias[bcol * 128 + wc * 64 + nj * 16 + lrow];

  #pragma unroll
  for (int mi = 0; mi < 4; ++mi) {
    #pragma unroll
    for (int r = 0; r < 4; ++r) {
      const int gr = brow * 128 + wr * 64 + mi * 16 + lk * 4 + r;   // C/D row
      const int bb = gr >> 10, s = gr & 1023;
      #pragma unroll
      for (int nj = 0; nj < 4; ++nj) {
        const int gc = bcol * 128 + wc * 64 + nj * 16 + lrow;       // C/D col
        const float v = acc[mi][nj][r] + bcv[nj];
        const int h = gc >> 6, d = gc & 63;
        const int bh = bb * 16 + h;
        if (p == 2)
          vtb[((size_t)bh * 64 + d) * 1024 + s] = f2bf(v);
        else
          ((p == 0) ? qbuf : kbuf)[((size_t)bh * 1024 + s) * 64 + d] = f2bf(v);
      }
    }
  }
}

// ---------------------------------------------------------------------------
// Kernel 4: flash attention.  Block = 4 waves, each wave owns 32 q-rows.
// K/V fragments read straight from global (L2-resident: 128KB per bh).
// P goes through a per-wave padded LDS tile to reach MFMA-A layout.
// ctx written (bf16) into cb [4096][1024] for the o-GEMM.
// ---------------------------------------------------------------------------
__global__ __launch_bounds__(256)
void attn_kernel(const short* __restrict__ qbuf, const short* __restrict__ kbuf,
                 const short* __restrict__ vtb, short* __restrict__ cb) {
  __shared__ short Pl[4][32 * 72];                  // stride 72 (16B-aligned, padded)
  const int qt = blockIdx.x, bh = blockIdx.y;
  const int tid = threadIdx.x, w = tid >> 6, lane = tid & 63;
  const int lrow = lane & 15, lk = lane >> 4;
  const short* Qp = qbuf + (size_t)bh * 65536;
  const short* Kp = kbuf + (size_t)bh * 65536;
  const short* Vp = vtb + (size_t)bh * 65536;
  const int q0 = qt * 128 + w * 32;
  short* pw = &Pl[w][0];

  bf16x8 aq[2][2];
  #pragma unroll
  for (int mi = 0; mi < 2; ++mi)
    #pragma unroll
    for (int kc = 0; kc < 2; ++kc)
      aq[mi][kc] = *(const bf16x8*)(Qp + (size_t)(q0 + mi * 16 + lrow) * 64 + kc * 32 + lk * 8);

  const f32x4 fz = {0.f, 0.f, 0.f, 0.f};
  float m_run[2][4], l_run[2][4];
  f32x4 acc_o[2][4];
  #pragma unroll
  for (int mi = 0; mi < 2; ++mi)
    #pragma unroll
    for (int j = 0; j < 4; ++j) {
      m_run[mi][j] = -1e30f;
      l_run[mi][j] = 0.f;
      acc_o[mi][j] = fz;
    }

  for (int tt = 0; tt < 16; ++tt) {
    const int t0 = tt * 64;
    bf16x8 bkf[4][2];
    #pragma unroll
    for (int nj = 0; nj < 4; ++nj)
      #pragma unroll
      for (int kc = 0; kc < 2; ++kc)
        bkf[nj][kc] = *(const bf16x8*)(Kp + (size_t)(t0 + nj * 16 + lrow) * 64 + kc * 32 + lk * 8);

    f32x4 sacc[2][4];
    #pragma unroll
    for (int mi = 0; mi < 2; ++mi)
      #pragma unroll
      for (int nj = 0; nj < 4; ++nj) sacc[mi][nj] = fz;
    #pragma unroll
    for (int kc = 0; kc < 2; ++kc)
      #pragma unroll
      for (int mi = 0; mi < 2; ++mi)
        #pragma unroll
        for (int nj = 0; nj < 4; ++nj)
          sacc[mi][nj] = __builtin_amdgcn_mfma_f32_16x16x32_bf16(aq[mi][kc], bkf[nj][kc], sacc[mi][nj], 0, 0, 0);

    #pragma unroll
    for (int mi = 0; mi < 2; ++mi)
      #pragma unroll
      for (int nj = 0; nj < 4; ++nj) sacc[mi][nj] *= 0.125f;   // 1/sqrt(64)

    #pragma unroll
    for (int mi = 0; mi < 2; ++mi) {
      #pragma unroll
      for (int r = 0; r < 4; ++r) {
        float tm = fmaxf(fmaxf(sacc[mi][0][r], sacc[mi][1][r]),
                         fmaxf(sacc[mi][2][r], sacc[mi][3][r]));
        tm = fmaxf(tm, __shfl_xor(tm, 1, 64));
        tm = fmaxf(tm, __shfl_xor(tm, 2, 64));
        tm = fmaxf(tm, __shfl_xor(tm, 4, 64));
        tm = fmaxf(tm, __shfl_xor(tm, 8, 64));
        const float mo = m_run[mi][r];
        const float mn = fmaxf(mo, tm);
        const float alpha = __expf(mo - mn);
        m_run[mi][r] = mn;
        float rs = 0.f;
        #pragma unroll
        for (int nj = 0; nj < 4; ++nj) {
          const float pv = __expf(sacc[mi][nj][r] - mn);
          sacc[mi][nj][r] = pv;
          rs += pv;
        }
        rs += __shfl_xor(rs, 1, 64);
        rs += __shfl_xor(rs, 2, 64);
        rs += __shfl_xor(rs, 4, 64);
        rs += __shfl_xor(rs, 8, 64);
        l_run[mi][r] = l_run[mi][r] * alpha + rs;
        #pragma unroll
        for (int dn = 0; dn < 4; ++dn) acc_o[mi][dn][r] *= alpha;
      }
    }

    // P (C/D layout) -> LDS -> re-read in MFMA-A layout (wave-local, no barrier)
    #pragma unroll
    for (int mi = 0; mi < 2; ++mi)
      #pragma unroll
      for (int r = 0; r < 4; ++r)
        #pragma unroll
        for (int nj = 0; nj < 4; ++nj)
          pw[(mi * 16 + lk * 4 + r) * 72 + nj * 16 + lrow] = f2bf(sacc[mi][nj][r]);

    #pragma unroll
    for (int kc = 0; kc < 2; ++kc) {
      bf16x8 pa[2];
      #pragma unroll
      for (int mi = 0; mi < 2; ++mi)
        pa[mi] = *(const bf16x8*)(pw + (mi * 16 + lrow) * 72 + kc * 32 + lk * 8);
      #pragma unroll
      for (int dn = 0; dn < 4; ++dn) {
        const bf16x8 bv8 = *(const bf16x8*)(Vp + (size_t)(dn * 16 + lrow) * 1024 + t0 + kc * 32 + lk * 8);
        #pragma unroll
        for (int mi = 0; mi < 2; ++mi)
          acc_o[mi][dn] = __builtin_amdgcn_mfma_f32_16x16x32_bf16(pa[mi], bv8, acc_o[mi][dn], 0, 0, 0);
      }
    }
  }

  const int bb = bh >> 4, h = bh & 15;
  #pragma unroll
  for (int mi = 0; mi < 2; ++mi) {
    #pragma unroll
    for (int r = 0; r < 4; ++r) {
      const float inv = 1.f / l_run[mi][r];
      const int s = q0 + mi * 16 + lk * 4 + r;
      const size_t gr = (size_t)(bb * 1024 + s) * 1024;
      #pragma unroll
      for (int dn = 0; dn < 4; ++dn) {
        const int col = h * 64 + dn * 16 + lrow;
        cb[gr + col] = f2bf(acc_o[mi][dn][r] * inv);
      }
    }
  }
}

// ---------------------------------------------------------------------------
// Kernel 5: o-projection -> fp32 d_out.
// ---------------------------------------------------------------------------
__global__ __launch_bounds__(256)
void gemm_o(const short* __restrict__ cb, const short* __restrict__ wo,
            const float* __restrict__ biaso, float* __restrict__ out) {
  __shared__ short As[128 * 64];
  __shared__ short Bs[128 * 64];
  const int brow = blockIdx.y, bcol = blockIdx.x;
  const f32x4 fz = {0.f, 0.f, 0.f, 0.f};
  f32x4 acc[4][4];
  #pragma unroll
  for (int a = 0; a < 4; ++a)
    #pragma unroll
    for (int b = 0; b < 4; ++b) acc[a][b] = fz;

  gemm_core(cb + (size_t)brow * 128 * 1024, wo + (size_t)bcol * 128 * 1024, As, Bs, acc);

  const int tid = threadIdx.x;
  const int wv = tid >> 6, lane = tid & 63;
  const int wr = wv >> 1, wc = wv & 1;
  const int lrow = lane & 15, lk = lane >> 4;
  float bcv[4];
  #pragma unroll
  for (int nj = 0; nj < 4; ++nj)
    bcv[nj] = biaso[bcol * 128 + wc * 64 + nj * 16 + lrow];

  #pragma unroll
  for (int mi = 0; mi < 4; ++mi) {
    #pragma unroll
    for (int r = 0; r < 4; ++r) {
      const int gr = brow * 128 + wr * 64 + mi * 16 + lk * 4 + r;
      #pragma unroll
      for (int nj = 0; nj < 4; ++nj) {
        const int gc = bcol * 128 + wc * 64 + nj * 16 + lrow;
        out[(size_t)gr * 1024 + gc] = acc[mi][nj][r] + bcv[nj];
      }
    }
  }
}

// ---------------------------------------------------------------------------
extern "C" void kernel_launch(void* const* d_in, const int* in_sizes, int n_in,
                              void* d_out, int out_size, void* d_ws, size_t ws_size,
                              hipStream_t stream) {
  (void)in_sizes; (void)n_in; (void)out_size; (void)ws_size;
  const float* x   = (const float*)d_in[0];
  const float* qw  = (const float*)d_in[1];
  const float* qb  = (const float*)d_in[2];
  const float* qla = (const float*)d_in[3];
  const float* qlb = (const float*)d_in[4];
  const float* kw  = (const float*)d_in[5];
  const float* kb  = (const float*)d_in[6];
  const float* kla = (const float*)d_in[7];
  const float* klb = (const float*)d_in[8];
  const float* vw  = (const float*)d_in[9];
  const float* vb  = (const float*)d_in[10];
  const float* vla = (const float*)d_in[11];
  const float* vlb = (const float*)d_in[12];
  const float* ow  = (const float*)d_in[13];
  const float* ob  = (const float*)d_in[14];
  const float* ola = (const float*)d_in[15];
  const float* olb = (const float*)d_in[16];

  short* xb   = (short*)d_ws;                         // 4096*1024 bf16 (reused as ctx)
  short* wb   = xb + (size_t)4096 * 1024;             // 4*1024*1024 bf16
  short* qbuf = wb + (size_t)4 * 1024 * 1024;         // 64*1024*64 each
  short* kbuf = qbuf + (size_t)4194304;
  short* vtb  = kbuf + (size_t)4194304;               // total 40 MB

  build_x<<<4096, 256, 0, stream>>>(x, xb);
  fold_w<<<dim3(1024, 4), 256, 0, stream>>>(qw, kw, vw, ow, qlb, klb, vlb, olb,
                                            qla, kla, vla, ola, wb);
  gemm_qkv<<<dim3(8, 32, 3), 256, 0, stream>>>(xb, wb, qb, kb, vb, qbuf, kbuf, vtb);
  attn_kernel<<<dim3(8, 64), 256, 0, stream>>>(qbuf, kbuf, vtb, xb);
  gemm_o<<<dim3(8, 32), 256, 0, stream>>>(xb, wb + (size_t)3 * 1024 * 1024, ob, (float*)d_out);
}

// Round 3
// 169.746 us; speedup vs baseline: 2.1824x; 1.0791x over previous
//
#include <hip/hip_runtime.h>
#include <cstdint>

// ---------------------------------------------------------------------------
// LoRA MHA: B=4,S=1024,E=1024,H=16,D=64,R=16.  bf16 MFMA, fp32 accum.
// LoRA folded into the weights: W' = W + B@A (scale=1).
// R3: attention rewritten with LDS-staged double-buffered K/V tiles and
// bh-major grid for XCD L2 locality.
// ---------------------------------------------------------------------------

typedef __attribute__((ext_vector_type(8))) short bf16x8;
typedef __attribute__((ext_vector_type(4))) float f32x4;
typedef __attribute__((ext_vector_type(4))) unsigned short u16x4;

__device__ __forceinline__ short f2bf(float f) {
  unsigned u = __builtin_bit_cast(unsigned, f);
  u += 0x7FFFu + ((u >> 16) & 1u);          // RNE
  return (short)(u >> 16);
}

typedef __attribute__((address_space(1))) const unsigned int as1_uint;
typedef __attribute__((address_space(3))) unsigned int as3_uint;

__device__ __forceinline__ void gload_lds16(const short* g, const short* l) {
  __builtin_amdgcn_global_load_lds((as1_uint*)g,
      (as3_uint*)(unsigned int)(uintptr_t)l, 16, 0, 0);
}

// ---------------------------------------------------------------------------
// Kernel 1: cast x (fp32) -> bf16 [4096][1024].
// ---------------------------------------------------------------------------
__global__ void build_x(const float* __restrict__ x, short* __restrict__ xb) {
  int idx = blockIdx.x * 256 + threadIdx.x;       // over 4096*256 float4 groups
  f32x4 v = ((const f32x4*)x)[idx];
  u16x4 o;
  o[0] = (unsigned short)f2bf(v[0]);
  o[1] = (unsigned short)f2bf(v[1]);
  o[2] = (unsigned short)f2bf(v[2]);
  o[3] = (unsigned short)f2bf(v[3]);
  ((u16x4*)xb)[idx] = o;
}

// ---------------------------------------------------------------------------
// Kernel 2: fold LoRA into weights: W'[p] = W_p + B_p @ A_p  (fp32 -> bf16).
// ---------------------------------------------------------------------------
__global__ void fold_w(const float* __restrict__ wq, const float* __restrict__ wk,
                       const float* __restrict__ wv, const float* __restrict__ wo,
                       const float* __restrict__ bq, const float* __restrict__ bk,
                       const float* __restrict__ bv, const float* __restrict__ bo,
                       const float* __restrict__ aq, const float* __restrict__ ak,
                       const float* __restrict__ av, const float* __restrict__ ao,
                       short* __restrict__ out) {
  const int p = blockIdx.y;
  const float* W  = (p == 0) ? wq : (p == 1) ? wk : (p == 2) ? wv : wo;
  const float* Bm = (p == 0) ? bq : (p == 1) ? bk : (p == 2) ? bv : bo;
  const float* A  = (p == 0) ? aq : (p == 1) ? ak : (p == 2) ? av : ao;
  const int idx = blockIdx.x * 256 + threadIdx.x;   // over 1024*256 e4-groups
  const int n = idx >> 8;
  const int e4 = idx & 255;
  f32x4 acc = ((const f32x4*)(W + (size_t)n * 1024))[e4];
  const float* br = Bm + n * 16;
  #pragma unroll
  for (int r = 0; r < 16; ++r) {
    const f32x4 a4 = ((const f32x4*)(A + (size_t)r * 1024))[e4];
    const float b = br[r];
    acc[0] += b * a4[0];
    acc[1] += b * a4[1];
    acc[2] += b * a4[2];
    acc[3] += b * a4[3];
  }
  u16x4 o;
  o[0] = (unsigned short)f2bf(acc[0]);
  o[1] = (unsigned short)f2bf(acc[1]);
  o[2] = (unsigned short)f2bf(acc[2]);
  o[3] = (unsigned short)f2bf(acc[3]);
  *(u16x4*)(out + (size_t)p * 1048576 + (size_t)idx * 4) = o;
}

// ---------------------------------------------------------------------------
// GEMM core: 128x128 tile, K=1024, BK=64, 4 waves (each 64x64 = 4x4 frags).
// ---------------------------------------------------------------------------
__device__ __forceinline__ void gemm_core(const short* __restrict__ xrow,
                                          const short* __restrict__ wrow,
                                          short* As, short* Bs,
                                          f32x4 (&acc)[4][4]) {
  const int tid = threadIdx.x;
  const int wv = tid >> 6, lane = tid & 63;
  const int wr = wv >> 1, wc = wv & 1;
  const int lrow = lane & 15, lk = lane >> 4;
  const int srow = lane >> 3, sphys = lane & 7;

  for (int kt = 0; kt < 16; ++kt) {
    #pragma unroll
    for (int i = 0; i < 4; ++i) {
      const int ch = i * 4 + wv;                  // 16 chunks of 8 rows
      const int row = ch * 8 + srow;
      const int sl = sphys ^ (row & 7);           // inverse-swizzled source
      gload_lds16(xrow + (size_t)row * 1024 + kt * 64 + sl * 8, As + ch * 512);
      gload_lds16(wrow + (size_t)row * 1024 + kt * 64 + sl * 8, Bs + ch * 512);
    }
    __syncthreads();
    #pragma unroll
    for (int kc = 0; kc < 2; ++kc) {
      bf16x8 af[4], bw[4];
      #pragma unroll
      for (int mi = 0; mi < 4; ++mi) {
        const int row = wr * 64 + mi * 16 + lrow;
        const int slot = (kc * 4 + lk) ^ (row & 7);
        af[mi] = *(const bf16x8*)(As + row * 64 + slot * 8);
      }
      #pragma unroll
      for (int nj = 0; nj < 4; ++nj) {
        const int row = wc * 64 + nj * 16 + lrow;
        const int slot = (kc * 4 + lk) ^ (row & 7);
        bw[nj] = *(const bf16x8*)(Bs + row * 64 + slot * 8);
      }
      #pragma unroll
      for (int mi = 0; mi < 4; ++mi)
        #pragma unroll
        for (int nj = 0; nj < 4; ++nj)
          acc[mi][nj] = __builtin_amdgcn_mfma_f32_16x16x32_bf16(af[mi], bw[nj], acc[mi][nj], 0, 0, 0);
    }
    __syncthreads();
  }
}

// ---------------------------------------------------------------------------
// Kernel 3: fused q/k/v projection (blockIdx.z = projection).
// q,k -> [bh][s][d] bf16 ; v -> transposed [bh][d][s] bf16.
// ---------------------------------------------------------------------------
__global__ __launch_bounds__(256)
void gemm_qkv(const short* __restrict__ xb, const short* __restrict__ wb,
              const float* __restrict__ biasq, const float* __restrict__ biask,
              const float* __restrict__ biasv,
              short* __restrict__ qbuf, short* __restrict__ kbuf, short* __restrict__ vtb) {
  __shared__ short As[128 * 64];
  __shared__ short Bs[128 * 64];
  const int p = blockIdx.z;
  const int brow = blockIdx.y, bcol = blockIdx.x;
  const f32x4 fz = {0.f, 0.f, 0.f, 0.f};
  f32x4 acc[4][4];
  #pragma unroll
  for (int a = 0; a < 4; ++a)
    #pragma unroll
    for (int b = 0; b < 4; ++b) acc[a][b] = fz;

  gemm_core(xb + (size_t)brow * 128 * 1024,
            wb + ((size_t)p * 1024 + (size_t)bcol * 128) * 1024, As, Bs, acc);

  const int tid = threadIdx.x;
  const int wv = tid >> 6, lane = tid & 63;
  const int wr = wv >> 1, wc = wv & 1;
  const int lrow = lane & 15, lk = lane >> 4;
  const float* bias = (p == 0) ? biasq : (p == 1) ? biask : biasv;
  float bcv[4];
  #pragma unroll
  for (int nj = 0; nj < 4; ++nj)
    bcv[nj] = bias[bcol * 128 + wc * 64 + nj * 16 + lrow];

  #pragma unroll
  for (int mi = 0; mi < 4; ++mi) {
    #pragma unroll
    for (int r = 0; r < 4; ++r) {
      const int gr = brow * 128 + wr * 64 + mi * 16 + lk * 4 + r;   // C/D row
      const int bb = gr >> 10, s = gr & 1023;
      #pragma unroll
      for (int nj = 0; nj < 4; ++nj) {
        const int gc = bcol * 128 + wc * 64 + nj * 16 + lrow;       // C/D col
        const float v = acc[mi][nj][r] + bcv[nj];
        const int h = gc >> 6, d = gc & 63;
        const int bh = bb * 16 + h;
        if (p == 2)
          vtb[((size_t)bh * 64 + d) * 1024 + s] = f2bf(v);
        else
          ((p == 0) ? qbuf : kbuf)[((size_t)bh * 1024 + s) * 64 + d] = f2bf(v);
      }
    }
  }
}

// ---------------------------------------------------------------------------
// Kernel 4: flash attention, LDS-staged K/V (double-buffered, XOR-swizzled).
// Grid (64 bh, 8 qt): linear wgid = qt*64+bh -> XCD = bh%8, so all q-tiles
// of one bh share one XCD's L2 (K/V fetched from HBM once).
// Block = 4 waves, each owns 32 q-rows; K/V tiles shared via LDS.
// ---------------------------------------------------------------------------
__global__ __launch_bounds__(256)
void attn_kernel(const short* __restrict__ qbuf, const short* __restrict__ kbuf,
                 const short* __restrict__ vtb, short* __restrict__ cb) {
  __shared__ short Ks[2][64 * 64];
  __shared__ short Vs[2][64 * 64];
  __shared__ short Pl[4][32 * 72];                  // per-wave, padded stride 72
  const int bh = blockIdx.x, qt = blockIdx.y;
  const int tid = threadIdx.x, w = tid >> 6, lane = tid & 63;
  const int lrow = lane & 15, lk = lane >> 4;
  const int srow = lane >> 3, sphys = lane & 7;
  const short* Qp = qbuf + (size_t)bh * 65536;
  const short* Kp = kbuf + (size_t)bh * 65536;
  const short* Vp = vtb + (size_t)bh * 65536;
  const int q0 = qt * 128 + w * 32;
  short* pw = &Pl[w][0];

  bf16x8 aq[2][2];
  #pragma unroll
  for (int mi = 0; mi < 2; ++mi)
    #pragma unroll
    for (int kc = 0; kc < 2; ++kc)
      aq[mi][kc] = *(const bf16x8*)(Qp + (size_t)(q0 + mi * 16 + lrow) * 64 + kc * 32 + lk * 8);

  const f32x4 fz = {0.f, 0.f, 0.f, 0.f};
  float m_run[2][4], l_run[2][4];
  f32x4 acc_o[2][4];
  #pragma unroll
  for (int mi = 0; mi < 2; ++mi)
    #pragma unroll
    for (int j = 0; j < 4; ++j) {
      m_run[mi][j] = -1e30f;
      l_run[mi][j] = 0.f;
      acc_o[mi][j] = fz;
    }

  // stage K/V tile tt into buffer buf: 64 rows x 64 cols bf16 each,
  // 2 chunks (8 rows) per wave per matrix, XOR-swizzled source columns.
  #define STAGE_KV(buf, tt)                                                  \
    {                                                                        \
      const int t0s = (tt) * 64;                                             \
      _Pragma("unroll")                                                      \
      for (int i = 0; i < 2; ++i) {                                          \
        const int ch = i * 4 + w;                                            \
        const int row = ch * 8 + srow;                                       \
        const int sl = sphys ^ (row & 7);                                    \
        gload_lds16(Kp + (size_t)(t0s + row) * 64 + sl * 8, Ks[buf] + ch * 512); \
        gload_lds16(Vp + (size_t)row * 1024 + t0s + sl * 8, Vs[buf] + ch * 512); \
      }                                                                      \
    }

  STAGE_KV(0, 0);
  __syncthreads();

  const float SCALE = 0.18033688f;   // (1/8) * log2(e)
  int cur = 0;
  for (int tt = 0; tt < 16; ++tt) {
    if (tt < 15) STAGE_KV(cur ^ 1, tt + 1);       // prefetch next tile

    // ---- QK^T from LDS ----
    bf16x8 bkf[4][2];
    #pragma unroll
    for (int nj = 0; nj < 4; ++nj) {
      const int row = nj * 16 + lrow;
      #pragma unroll
      for (int kc = 0; kc < 2; ++kc) {
        const int slot = (kc * 4 + lk) ^ (row & 7);
        bkf[nj][kc] = *(const bf16x8*)(Ks[cur] + row * 64 + slot * 8);
      }
    }

    f32x4 sacc[2][4];
    #pragma unroll
    for (int mi = 0; mi < 2; ++mi)
      #pragma unroll
      for (int nj = 0; nj < 4; ++nj) sacc[mi][nj] = fz;
    #pragma unroll
    for (int kc = 0; kc < 2; ++kc)
      #pragma unroll
      for (int mi = 0; mi < 2; ++mi)
        #pragma unroll
        for (int nj = 0; nj < 4; ++nj)
          sacc[mi][nj] = __builtin_amdgcn_mfma_f32_16x16x32_bf16(aq[mi][kc], bkf[nj][kc], sacc[mi][nj], 0, 0, 0);

    #pragma unroll
    for (int mi = 0; mi < 2; ++mi)
      #pragma unroll
      for (int nj = 0; nj < 4; ++nj) sacc[mi][nj] *= SCALE;   // log2-domain

    // ---- online softmax (base 2) ----
    #pragma unroll
    for (int mi = 0; mi < 2; ++mi) {
      #pragma unroll
      for (int r = 0; r < 4; ++r) {
        float tm = fmaxf(fmaxf(sacc[mi][0][r], sacc[mi][1][r]),
                         fmaxf(sacc[mi][2][r], sacc[mi][3][r]));
        tm = fmaxf(tm, __shfl_xor(tm, 1, 64));
        tm = fmaxf(tm, __shfl_xor(tm, 2, 64));
        tm = fmaxf(tm, __shfl_xor(tm, 4, 64));
        tm = fmaxf(tm, __shfl_xor(tm, 8, 64));
        const float mo = m_run[mi][r];
        const float mn = fmaxf(mo, tm);
        const float alpha = exp2f(mo - mn);
        m_run[mi][r] = mn;
        float rs = 0.f;
        #pragma unroll
        for (int nj = 0; nj < 4; ++nj) {
          const float pv = exp2f(sacc[mi][nj][r] - mn);
          sacc[mi][nj][r] = pv;
          rs += pv;
        }
        rs += __shfl_xor(rs, 1, 64);
        rs += __shfl_xor(rs, 2, 64);
        rs += __shfl_xor(rs, 4, 64);
        rs += __shfl_xor(rs, 8, 64);
        l_run[mi][r] = l_run[mi][r] * alpha + rs;
        #pragma unroll
        for (int dn = 0; dn < 4; ++dn) acc_o[mi][dn][r] *= alpha;
      }
    }

    // ---- P (C/D layout) -> LDS -> MFMA-A layout (wave-local) ----
    #pragma unroll
    for (int mi = 0; mi < 2; ++mi)
      #pragma unroll
      for (int r = 0; r < 4; ++r)
        #pragma unroll
        for (int nj = 0; nj < 4; ++nj)
          pw[(mi * 16 + lk * 4 + r) * 72 + nj * 16 + lrow] = f2bf(sacc[mi][nj][r]);

    #pragma unroll
    for (int kc = 0; kc < 2; ++kc) {
      bf16x8 pa[2];
      #pragma unroll
      for (int mi = 0; mi < 2; ++mi)
        pa[mi] = *(const bf16x8*)(pw + (mi * 16 + lrow) * 72 + kc * 32 + lk * 8);
      #pragma unroll
      for (int dn = 0; dn < 4; ++dn) {
        const int row = dn * 16 + lrow;
        const int slot = (kc * 4 + lk) ^ (row & 7);
        const bf16x8 bv8 = *(const bf16x8*)(Vs[cur] + row * 64 + slot * 8);
        #pragma unroll
        for (int mi = 0; mi < 2; ++mi)
          acc_o[mi][dn] = __builtin_amdgcn_mfma_f32_16x16x32_bf16(pa[mi], bv8, acc_o[mi][dn], 0, 0, 0);
      }
    }

    __syncthreads();      // prefetch landed; LDS reads of cur done in all waves
    cur ^= 1;
  }

  const int bb = bh >> 4, h = bh & 15;
  #pragma unroll
  for (int mi = 0; mi < 2; ++mi) {
    #pragma unroll
    for (int r = 0; r < 4; ++r) {
      const float inv = 1.f / l_run[mi][r];
      const int s = q0 + mi * 16 + lk * 4 + r;
      const size_t gr = (size_t)(bb * 1024 + s) * 1024;
      #pragma unroll
      for (int dn = 0; dn < 4; ++dn) {
        const int col = h * 64 + dn * 16 + lrow;
        cb[gr + col] = f2bf(acc_o[mi][dn][r] * inv);
      }
    }
  }
  #undef STAGE_KV
}

// ---------------------------------------------------------------------------
// Kernel 5: o-projection -> fp32 d_out.
// ---------------------------------------------------------------------------
__global__ __launch_bounds__(256)
void gemm_o(const short* __restrict__ cb, const short* __restrict__ wo,
            const float* __restrict__ biaso, float* __restrict__ out) {
  __shared__ short As[128 * 64];
  __shared__ short Bs[128 * 64];
  const int brow = blockIdx.y, bcol = blockIdx.x;
  const f32x4 fz = {0.f, 0.f, 0.f, 0.f};
  f32x4 acc[4][4];
  #pragma unroll
  for (int a = 0; a < 4; ++a)
    #pragma unroll
    for (int b = 0; b < 4; ++b) acc[a][b] = fz;

  gemm_core(cb + (size_t)brow * 128 * 1024, wo + (size_t)bcol * 128 * 1024, As, Bs, acc);

  const int tid = threadIdx.x;
  const int wv = tid >> 6, lane = tid & 63;
  const int wr = wv >> 1, wc = wv & 1;
  const int lrow = lane & 15, lk = lane >> 4;
  float bcv[4];
  #pragma unroll
  for (int nj = 0; nj < 4; ++nj)
    bcv[nj] = biaso[bcol * 128 + wc * 64 + nj * 16 + lrow];

  #pragma unroll
  for (int mi = 0; mi < 4; ++mi) {
    #pragma unroll
    for (int r = 0; r < 4; ++r) {
      const int gr = brow * 128 + wr * 64 + mi * 16 + lk * 4 + r;
      #pragma unroll
      for (int nj = 0; nj < 4; ++nj) {
        const int gc = bcol * 128 + wc * 64 + nj * 16 + lrow;
        out[(size_t)gr * 1024 + gc] = acc[mi][nj][r] + bcv[nj];
      }
    }
  }
}

// ---------------------------------------------------------------------------
extern "C" void kernel_launch(void* const* d_in, const int* in_sizes, int n_in,
                              void* d_out, int out_size, void* d_ws, size_t ws_size,
                              hipStream_t stream) {
  (void)in_sizes; (void)n_in; (void)out_size; (void)ws_size;
  const float* x   = (const float*)d_in[0];
  const float* qw  = (const float*)d_in[1];
  const float* qb  = (const float*)d_in[2];
  const float* qla = (const float*)d_in[3];
  const float* qlb = (const float*)d_in[4];
  const float* kw  = (const float*)d_in[5];
  const float* kb  = (const float*)d_in[6];
  const float* kla = (const float*)d_in[7];
  const float* klb = (const float*)d_in[8];
  const float* vw  = (const float*)d_in[9];
  const float* vb  = (const float*)d_in[10];
  const float* vla = (const float*)d_in[11];
  const float* vlb = (const float*)d_in[12];
  const float* ow  = (const float*)d_in[13];
  const float* ob  = (const float*)d_in[14];
  const float* ola = (const float*)d_in[15];
  const float* olb = (const float*)d_in[16];

  short* xb   = (short*)d_ws;                         // 4096*1024 bf16 (reused as ctx)
  short* wb   = xb + (size_t)4096 * 1024;             // 4*1024*1024 bf16
  short* qbuf = wb + (size_t)4 * 1024 * 1024;         // 64*1024*64 each
  short* kbuf = qbuf + (size_t)4194304;
  short* vtb  = kbuf + (size_t)4194304;               // total 40 MB

  build_x<<<4096, 256, 0, stream>>>(x, xb);
  fold_w<<<dim3(1024, 4), 256, 0, stream>>>(qw, kw, vw, ow, qlb, klb, vlb, olb,
                                            qla, kla, vla, ola, wb);
  gemm_qkv<<<dim3(8, 32, 3), 256, 0, stream>>>(xb, wb, qb, kb, vb, qbuf, kbuf, vtb);
  attn_kernel<<<dim3(64, 8), 256, 0, stream>>>(qbuf, kbuf, vtb, xb);
  gemm_o<<<dim3(8, 32), 256, 0, stream>>>(xb, wb + (size_t)3 * 1024 * 1024, ob, (float*)d_out);
}

// Round 4
// 141.054 us; speedup vs baseline: 2.6264x; 1.2034x over previous
//
#include <hip/hip_runtime.h>
#include <cstdint>

// ---------------------------------------------------------------------------
// LoRA MHA: B=4,S=1024,E=1024,H=16,D=64,R=16.  bf16 MFMA, fp32 accum.
// LoRA folded into the weights: W' = W + B@A (scale=1).
// R4: attention uses swapped 32x32 QK^T (S^T = K·Q^T) so softmax is
// lane-local per q-row; P->PV fragments via cvt_pk_bf16 + permlane32_swap
// (T12); PV also swapped (O^T = V^T·P^T) so alpha-rescale is lane-local.
// softmax scale*log2(e) folded into q-projection epilogue.
// ---------------------------------------------------------------------------

typedef __attribute__((ext_vector_type(8))) short bf16x8;
typedef __attribute__((ext_vector_type(4))) float f32x4;
typedef __attribute__((ext_vector_type(16))) float f32x16;
typedef __attribute__((ext_vector_type(4))) unsigned short u16x4;
typedef __attribute__((ext_vector_type(4))) unsigned int u32x4;

__device__ __forceinline__ short f2bf(float f) {
  unsigned u = __builtin_bit_cast(unsigned, f);
  u += 0x7FFFu + ((u >> 16) & 1u);          // RNE
  return (short)(u >> 16);
}

typedef __attribute__((address_space(1))) const unsigned int as1_uint;
typedef __attribute__((address_space(3))) unsigned int as3_uint;

__device__ __forceinline__ void gload_lds16(const short* g, const short* l) {
  __builtin_amdgcn_global_load_lds((as1_uint*)g,
      (as3_uint*)(unsigned int)(uintptr_t)l, 16, 0, 0);
}

__device__ __forceinline__ unsigned cvtpk(float lo, float hi) {
  unsigned r;
  asm("v_cvt_pk_bf16_f32 %0, %1, %2" : "=v"(r) : "v"(lo), "v"(hi));
  return r;
}
__device__ __forceinline__ void plswap(unsigned &a, unsigned &b) {
  asm("v_permlane32_swap_b32 %0, %1" : "+v"(a), "+v"(b));
}

// Build the two K=16 B-fragments (P^T[k][q]) of one 32x32 S^T tile from the
// 16 fp32 C/D regs.  Layout: held k=(reg&3)+8*(reg>>2)+4*hi, col q=lane&31;
// frag word w of half c needs k-pair (c*16+hi*8+2w, +1).  swap(X0,X2)
// produces words w0/w2; swap(X1,X3) produces w1/w3 (see derivation).
__device__ __forceinline__ void build_pfrag(const f32x16 &s, bf16x8 &f0, bf16x8 &f1) {
  unsigned x0 = cvtpk(s[0], s[1]),  x1 = cvtpk(s[2], s[3]);
  unsigned x2 = cvtpk(s[4], s[5]),  x3 = cvtpk(s[6], s[7]);
  plswap(x0, x2); plswap(x1, x3);
  unsigned y0 = cvtpk(s[8], s[9]),  y1 = cvtpk(s[10], s[11]);
  unsigned y2 = cvtpk(s[12], s[13]), y3 = cvtpk(s[14], s[15]);
  plswap(y0, y2); plswap(y1, y3);
  u32x4 a = {x0, x1, x2, x3}, b = {y0, y1, y2, y3};
  f0 = __builtin_bit_cast(bf16x8, a);
  f1 = __builtin_bit_cast(bf16x8, b);
}

// ---------------------------------------------------------------------------
// Kernel 1: cast x (fp32) -> bf16 [4096][1024].
// ---------------------------------------------------------------------------
__global__ void build_x(const float* __restrict__ x, short* __restrict__ xb) {
  int idx = blockIdx.x * 256 + threadIdx.x;       // over 4096*256 float4 groups
  f32x4 v = ((const f32x4*)x)[idx];
  u16x4 o;
  o[0] = (unsigned short)f2bf(v[0]);
  o[1] = (unsigned short)f2bf(v[1]);
  o[2] = (unsigned short)f2bf(v[2]);
  o[3] = (unsigned short)f2bf(v[3]);
  ((u16x4*)xb)[idx] = o;
}

// ---------------------------------------------------------------------------
// Kernel 2: fold LoRA into weights: W'[p] = W_p + B_p @ A_p  (fp32 -> bf16).
// ---------------------------------------------------------------------------
__global__ void fold_w(const float* __restrict__ wq, const float* __restrict__ wk,
                       const float* __restrict__ wv, const float* __restrict__ wo,
                       const float* __restrict__ bq, const float* __restrict__ bk,
                       const float* __restrict__ bv, const float* __restrict__ bo,
                       const float* __restrict__ aq, const float* __restrict__ ak,
                       const float* __restrict__ av, const float* __restrict__ ao,
                       short* __restrict__ out) {
  const int p = blockIdx.y;
  const float* W  = (p == 0) ? wq : (p == 1) ? wk : (p == 2) ? wv : wo;
  const float* Bm = (p == 0) ? bq : (p == 1) ? bk : (p == 2) ? bv : bo;
  const float* A  = (p == 0) ? aq : (p == 1) ? ak : (p == 2) ? av : ao;
  const int idx = blockIdx.x * 256 + threadIdx.x;   // over 1024*256 e4-groups
  const int n = idx >> 8;
  const int e4 = idx & 255;
  f32x4 acc = ((const f32x4*)(W + (size_t)n * 1024))[e4];
  const float* br = Bm + n * 16;
  #pragma unroll
  for (int r = 0; r < 16; ++r) {
    const f32x4 a4 = ((const f32x4*)(A + (size_t)r * 1024))[e4];
    const float b = br[r];
    acc[0] += b * a4[0];
    acc[1] += b * a4[1];
    acc[2] += b * a4[2];
    acc[3] += b * a4[3];
  }
  u16x4 o;
  o[0] = (unsigned short)f2bf(acc[0]);
  o[1] = (unsigned short)f2bf(acc[1]);
  o[2] = (unsigned short)f2bf(acc[2]);
  o[3] = (unsigned short)f2bf(acc[3]);
  *(u16x4*)(out + (size_t)p * 1048576 + (size_t)idx * 4) = o;
}

// ---------------------------------------------------------------------------
// GEMM core: 128x128 tile, K=1024, BK=64, 4 waves (each 64x64 = 4x4 frags).
// ---------------------------------------------------------------------------
__device__ __forceinline__ void gemm_core(const short* __restrict__ xrow,
                                          const short* __restrict__ wrow,
                                          short* As, short* Bs,
                                          f32x4 (&acc)[4][4]) {
  const int tid = threadIdx.x;
  const int wv = tid >> 6, lane = tid & 63;
  const int wr = wv >> 1, wc = wv & 1;
  const int lrow = lane & 15, lk = lane >> 4;
  const int srow = lane >> 3, sphys = lane & 7;

  for (int kt = 0; kt < 16; ++kt) {
    #pragma unroll
    for (int i = 0; i < 4; ++i) {
      const int ch = i * 4 + wv;                  // 16 chunks of 8 rows
      const int row = ch * 8 + srow;
      const int sl = sphys ^ (row & 7);           // inverse-swizzled source
      gload_lds16(xrow + (size_t)row * 1024 + kt * 64 + sl * 8, As + ch * 512);
      gload_lds16(wrow + (size_t)row * 1024 + kt * 64 + sl * 8, Bs + ch * 512);
    }
    __syncthreads();
    #pragma unroll
    for (int kc = 0; kc < 2; ++kc) {
      bf16x8 af[4], bw[4];
      #pragma unroll
      for (int mi = 0; mi < 4; ++mi) {
        const int row = wr * 64 + mi * 16 + lrow;
        const int slot = (kc * 4 + lk) ^ (row & 7);
        af[mi] = *(const bf16x8*)(As + row * 64 + slot * 8);
      }
      #pragma unroll
      for (int nj = 0; nj < 4; ++nj) {
        const int row = wc * 64 + nj * 16 + lrow;
        const int slot = (kc * 4 + lk) ^ (row & 7);
        bw[nj] = *(const bf16x8*)(Bs + row * 64 + slot * 8);
      }
      #pragma unroll
      for (int mi = 0; mi < 4; ++mi)
        #pragma unroll
        for (int nj = 0; nj < 4; ++nj)
          acc[mi][nj] = __builtin_amdgcn_mfma_f32_16x16x32_bf16(af[mi], bw[nj], acc[mi][nj], 0, 0, 0);
    }
    __syncthreads();
  }
}

// ---------------------------------------------------------------------------
// Kernel 3: fused q/k/v projection (blockIdx.z = projection).
// q (scaled by log2(e)/8) , k -> [bh][s][d] bf16 ; v -> [bh][d][s] bf16.
// ---------------------------------------------------------------------------
__global__ __launch_bounds__(256)
void gemm_qkv(const short* __restrict__ xb, const short* __restrict__ wb,
              const float* __restrict__ biasq, const float* __restrict__ biask,
              const float* __restrict__ biasv,
              short* __restrict__ qbuf, short* __restrict__ kbuf, short* __restrict__ vtb) {
  __shared__ short As[128 * 64];
  __shared__ short Bs[128 * 64];
  const int p = blockIdx.z;
  const int brow = blockIdx.y, bcol = blockIdx.x;
  const f32x4 fz = {0.f, 0.f, 0.f, 0.f};
  f32x4 acc[4][4];
  #pragma unroll
  for (int a = 0; a < 4; ++a)
    #pragma unroll
    for (int b = 0; b < 4; ++b) acc[a][b] = fz;

  gemm_core(xb + (size_t)brow * 128 * 1024,
            wb + ((size_t)p * 1024 + (size_t)bcol * 128) * 1024, As, Bs, acc);

  const int tid = threadIdx.x;
  const int wv = tid >> 6, lane = tid & 63;
  const int wr = wv >> 1, wc = wv & 1;
  const int lrow = lane & 15, lk = lane >> 4;
  const float* bias = (p == 0) ? biasq : (p == 1) ? biask : biasv;
  const float oscale = (p == 0) ? 0.18033688f : 1.0f;   // log2(e)/8 folded into q
  float bcv[4];
  #pragma unroll
  for (int nj = 0; nj < 4; ++nj)
    bcv[nj] = bias[bcol * 128 + wc * 64 + nj * 16 + lrow];

  #pragma unroll
  for (int mi = 0; mi < 4; ++mi) {
    #pragma unroll
    for (int r = 0; r < 4; ++r) {
      const int gr = brow * 128 + wr * 64 + mi * 16 + lk * 4 + r;   // C/D row
      const int bb = gr >> 10, s = gr & 1023;
      #pragma unroll
      for (int nj = 0; nj < 4; ++nj) {
        const int gc = bcol * 128 + wc * 64 + nj * 16 + lrow;       // C/D col
        const float v = (acc[mi][nj][r] + bcv[nj]) * oscale;
        const int h = gc >> 6, d = gc & 63;
        const int bh = bb * 16 + h;
        if (p == 2)
          vtb[((size_t)bh * 64 + d) * 1024 + s] = f2bf(v);
        else
          ((p == 0) ? qbuf : kbuf)[((size_t)bh * 1024 + s) * 64 + d] = f2bf(v);
      }
    }
  }
}

// ---------------------------------------------------------------------------
// Kernel 4: flash attention, swapped 32x32 MFMA form.
// Grid (64 bh, 8 qt); block = 4 waves, each wave owns 32 q-rows.
// S^T[k][q] = mfma32x32x16(A=K, B=Q): lane holds 32 k-scores of q=lane&31.
// O^T[d][q] = mfma(A=V^T, B=P^T): acc cols = q -> alpha rescale lane-local.
// ---------------------------------------------------------------------------
__global__ __launch_bounds__(256)
void attn_kernel(const short* __restrict__ qbuf, const short* __restrict__ kbuf,
                 const short* __restrict__ vtb, short* __restrict__ cb) {
  __shared__ short Ks[2][64 * 64];
  __shared__ short Vs[2][64 * 64];
  const int bh = blockIdx.x, qt = blockIdx.y;
  const int tid = threadIdx.x, w = tid >> 6, lane = tid & 63;
  const int l31 = lane & 31, hi = lane >> 5;
  const int srow = lane >> 3, sphys = lane & 7;
  const short* Qp = qbuf + (size_t)bh * 65536;
  const short* Kp = kbuf + (size_t)bh * 65536;
  const short* Vp = vtb + (size_t)bh * 65536;
  const int q0 = qt * 128 + w * 32;

  // Q as B-fragments: B[d][q], lane: q=l31, d = kc*16 + hi*8 + j.
  bf16x8 bq[4];
  #pragma unroll
  for (int kc = 0; kc < 4; ++kc)
    bq[kc] = *(const bf16x8*)(Qp + (size_t)(q0 + l31) * 64 + kc * 16 + hi * 8);

  const f32x16 fz16 = {0.f,0.f,0.f,0.f,0.f,0.f,0.f,0.f,0.f,0.f,0.f,0.f,0.f,0.f,0.f,0.f};
  float m_run = -1e30f, l_run = 0.f;
  f32x16 acc0 = fz16, acc1 = fz16;        // O^T, dn = 0,1 (d-halves)

  #define STAGE_KV(buf, tt)                                                  \
    {                                                                        \
      const int t0s = (tt) * 64;                                             \
      _Pragma("unroll")                                                      \
      for (int i = 0; i < 2; ++i) {                                          \
        const int ch = i * 4 + w;                                            \
        const int row = ch * 8 + srow;                                       \
        const int sl = sphys ^ (row & 7);                                    \
        gload_lds16(Kp + (size_t)(t0s + row) * 64 + sl * 8, Ks[buf] + ch * 512); \
        gload_lds16(Vp + (size_t)row * 1024 + t0s + sl * 8, Vs[buf] + ch * 512); \
      }                                                                      \
    }

  STAGE_KV(0, 0);
  __syncthreads();

  int cur = 0;
  for (int tt = 0; tt < 16; ++tt) {
    if (tt < 15) STAGE_KV(cur ^ 1, tt + 1);       // prefetch next tile

    // ---- S^T = K · Q^T : two 32(k)x32(q) tiles, contraction d=64 ----
    f32x16 s0 = fz16, s1 = fz16;
    #pragma unroll
    for (int kc = 0; kc < 4; ++kc) {
      const int slot = (kc * 2 + hi) ^ (l31 & 7);
      const bf16x8 ak0 = *(const bf16x8*)(Ks[cur] + l31 * 64 + slot * 8);
      const bf16x8 ak1 = *(const bf16x8*)(Ks[cur] + (32 + l31) * 64 + slot * 8);
      s0 = __builtin_amdgcn_mfma_f32_32x32x16_bf16(ak0, bq[kc], s0, 0, 0, 0);
      s1 = __builtin_amdgcn_mfma_f32_32x32x16_bf16(ak1, bq[kc], s1, 0, 0, 0);
    }

    // ---- online softmax, log2 domain (scale folded into q) ----
    float tm = s0[0];
    #pragma unroll
    for (int r = 1; r < 16; ++r) tm = fmaxf(tm, s0[r]);
    #pragma unroll
    for (int r = 0; r < 16; ++r) tm = fmaxf(tm, s1[r]);
    tm = fmaxf(tm, __shfl_xor(tm, 32, 64));
    const float mn = fmaxf(m_run, tm);
    const float alpha = exp2f(m_run - mn);
    m_run = mn;
    float rs = 0.f;
    #pragma unroll
    for (int r = 0; r < 16; ++r) { const float p = exp2f(s0[r] - mn); s0[r] = p; rs += p; }
    #pragma unroll
    for (int r = 0; r < 16; ++r) { const float p = exp2f(s1[r] - mn); s1[r] = p; rs += p; }
    rs += __shfl_xor(rs, 32, 64);
    l_run = l_run * alpha + rs;
    #pragma unroll
    for (int r = 0; r < 16; ++r) { acc0[r] *= alpha; acc1[r] *= alpha; }

    // ---- P^T fragments (in-register, T12) ----
    bf16x8 pf[4];
    build_pfrag(s0, pf[0], pf[1]);
    build_pfrag(s1, pf[2], pf[3]);

    // ---- O^T += V^T · P^T ----
    #pragma unroll
    for (int kc4 = 0; kc4 < 4; ++kc4) {
      const int slot = (kc4 * 2 + hi) ^ (l31 & 7);
      const bf16x8 av0 = *(const bf16x8*)(Vs[cur] + l31 * 64 + slot * 8);
      const bf16x8 av1 = *(const bf16x8*)(Vs[cur] + (32 + l31) * 64 + slot * 8);
      acc0 = __builtin_amdgcn_mfma_f32_32x32x16_bf16(av0, pf[kc4], acc0, 0, 0, 0);
      acc1 = __builtin_amdgcn_mfma_f32_32x32x16_bf16(av1, pf[kc4], acc1, 0, 0, 0);
    }

    __syncthreads();      // prefetch landed; LDS reads of cur done in all waves
    cur ^= 1;
  }

  // ---- write ctx: lane owns q-row s = q0+l31; d = dn*32+(r&3)+8*(r>>2)+4*hi
  const int bb = bh >> 4, h = bh & 15;
  const int s = q0 + l31;
  short* crow = cb + (size_t)(bb * 1024 + s) * 1024 + h * 64;
  const float inv = 1.f / l_run;
  #pragma unroll
  for (int rp = 0; rp < 8; ++rp) {
    const int r = rp * 2;
    const int d = (r & 3) + 8 * (r >> 2) + 4 * hi;
    const unsigned p0 = (unsigned)(unsigned short)f2bf(acc0[r] * inv)
                      | ((unsigned)(unsigned short)f2bf(acc0[r + 1] * inv) << 16);
    const unsigned p1 = (unsigned)(unsigned short)f2bf(acc1[r] * inv)
                      | ((unsigned)(unsigned short)f2bf(acc1[r + 1] * inv) << 16);
    *(unsigned*)(crow + d) = p0;
    *(unsigned*)(crow + 32 + d) = p1;
  }
  #undef STAGE_KV
}

// ---------------------------------------------------------------------------
// Kernel 5: o-projection -> fp32 d_out.
// ---------------------------------------------------------------------------
__global__ __launch_bounds__(256)
void gemm_o(const short* __restrict__ cb, const short* __restrict__ wo,
            const float* __restrict__ biaso, float* __restrict__ out) {
  __shared__ short As[128 * 64];
  __shared__ short Bs[128 * 64];
  const int brow = blockIdx.y, bcol = blockIdx.x;
  const f32x4 fz = {0.f, 0.f, 0.f, 0.f};
  f32x4 acc[4][4];
  #pragma unroll
  for (int a = 0; a < 4; ++a)
    #pragma unroll
    for (int b = 0; b < 4; ++b) acc[a][b] = fz;

  gemm_core(cb + (size_t)brow * 128 * 1024, wo + (size_t)bcol * 128 * 1024, As, Bs, acc);

  const int tid = threadIdx.x;
  const int wv = tid >> 6, lane = tid & 63;
  const int wr = wv >> 1, wc = wv & 1;
  const int lrow = lane & 15, lk = lane >> 4;
  float bcv[4];
  #pragma unroll
  for (int nj = 0; nj < 4; ++nj)
    bcv[nj] = biaso[bcol * 128 + wc * 64 + nj * 16 + lrow];

  #pragma unroll
  for (int mi = 0; mi < 4; ++mi) {
    #pragma unroll
    for (int r = 0; r < 4; ++r) {
      const int gr = brow * 128 + wr * 64 + mi * 16 + lk * 4 + r;
      #pragma unroll
      for (int nj = 0; nj < 4; ++nj) {
        const int gc = bcol * 128 + wc * 64 + nj * 16 + lrow;
        out[(size_t)gr * 1024 + gc] = acc[mi][nj][r] + bcv[nj];
      }
    }
  }
}

// ---------------------------------------------------------------------------
extern "C" void kernel_launch(void* const* d_in, const int* in_sizes, int n_in,
                              void* d_out, int out_size, void* d_ws, size_t ws_size,
                              hipStream_t stream) {
  (void)in_sizes; (void)n_in; (void)out_size; (void)ws_size;
  const float* x   = (const float*)d_in[0];
  const float* qw  = (const float*)d_in[1];
  const float* qb  = (const float*)d_in[2];
  const float* qla = (const float*)d_in[3];
  const float* qlb = (const float*)d_in[4];
  const float* kw  = (const float*)d_in[5];
  const float* kb  = (const float*)d_in[6];
  const float* kla = (const float*)d_in[7];
  const float* klb = (const float*)d_in[8];
  const float* vw  = (const float*)d_in[9];
  const float* vb  = (const float*)d_in[10];
  const float* vla = (const float*)d_in[11];
  const float* vlb = (const float*)d_in[12];
  const float* ow  = (const float*)d_in[13];
  const float* ob  = (const float*)d_in[14];
  const float* ola = (const float*)d_in[15];
  const float* olb = (const float*)d_in[16];

  short* xb   = (short*)d_ws;                         // 4096*1024 bf16 (reused as ctx)
  short* wb   = xb + (size_t)4096 * 1024;             // 4*1024*1024 bf16
  short* qbuf = wb + (size_t)4 * 1024 * 1024;         // 64*1024*64 each
  short* kbuf = qbuf + (size_t)4194304;
  short* vtb  = kbuf + (size_t)4194304;               // total 40 MB

  build_x<<<4096, 256, 0, stream>>>(x, xb);
  fold_w<<<dim3(1024, 4), 256, 0, stream>>>(qw, kw, vw, ow, qlb, klb, vlb, olb,
                                            qla, kla, vla, ola, wb);
  gemm_qkv<<<dim3(8, 32, 3), 256, 0, stream>>>(xb, wb, qb, kb, vb, qbuf, kbuf, vtb);
  attn_kernel<<<dim3(64, 8), 256, 0, stream>>>(qbuf, kbuf, vtb, xb);
  gemm_o<<<dim3(8, 32), 256, 0, stream>>>(xb, wb + (size_t)3 * 1024 * 1024, ob, (float*)d_out);
}

// Round 5
// 137.305 us; speedup vs baseline: 2.6981x; 1.0273x over previous
//
#include <hip/hip_runtime.h>
#include <cstdint>

// ---------------------------------------------------------------------------
// LoRA MHA: B=4,S=1024,E=1024,H=16,D=64,R=16.  bf16 MFMA, fp32 accum.
// LoRA folded into the weights: W' = W + B@A (scale=1).
// R5: GEMMs use double-buffered 2-phase K-loop (prefetch-before-compute) and
// the q/k/v projections are merged into one N=3072 GEMM with a bijective
// XCD-locality swizzle (each XCD owns 3 W-panels, walks A brow-major).
// ---------------------------------------------------------------------------

typedef __attribute__((ext_vector_type(8))) short bf16x8;
typedef __attribute__((ext_vector_type(4))) float f32x4;
typedef __attribute__((ext_vector_type(16))) float f32x16;
typedef __attribute__((ext_vector_type(4))) unsigned short u16x4;
typedef __attribute__((ext_vector_type(4))) unsigned int u32x4;

__device__ __forceinline__ short f2bf(float f) {
  unsigned u = __builtin_bit_cast(unsigned, f);
  u += 0x7FFFu + ((u >> 16) & 1u);          // RNE
  return (short)(u >> 16);
}

typedef __attribute__((address_space(1))) const unsigned int as1_uint;
typedef __attribute__((address_space(3))) unsigned int as3_uint;

__device__ __forceinline__ void gload_lds16(const short* g, const short* l) {
  __builtin_amdgcn_global_load_lds((as1_uint*)g,
      (as3_uint*)(unsigned int)(uintptr_t)l, 16, 0, 0);
}

__device__ __forceinline__ unsigned cvtpk(float lo, float hi) {
  unsigned r;
  asm("v_cvt_pk_bf16_f32 %0, %1, %2" : "=v"(r) : "v"(lo), "v"(hi));
  return r;
}
__device__ __forceinline__ void plswap(unsigned &a, unsigned &b) {
  asm("v_permlane32_swap_b32 %0, %1" : "+v"(a), "+v"(b));
}

__device__ __forceinline__ void build_pfrag(const f32x16 &s, bf16x8 &f0, bf16x8 &f1) {
  unsigned x0 = cvtpk(s[0], s[1]),  x1 = cvtpk(s[2], s[3]);
  unsigned x2 = cvtpk(s[4], s[5]),  x3 = cvtpk(s[6], s[7]);
  plswap(x0, x2); plswap(x1, x3);
  unsigned y0 = cvtpk(s[8], s[9]),  y1 = cvtpk(s[10], s[11]);
  unsigned y2 = cvtpk(s[12], s[13]), y3 = cvtpk(s[14], s[15]);
  plswap(y0, y2); plswap(y1, y3);
  u32x4 a = {x0, x1, x2, x3}, b = {y0, y1, y2, y3};
  f0 = __builtin_bit_cast(bf16x8, a);
  f1 = __builtin_bit_cast(bf16x8, b);
}

// ---------------------------------------------------------------------------
// Kernel 1: cast x (fp32) -> bf16 [4096][1024].
// ---------------------------------------------------------------------------
__global__ void build_x(const float* __restrict__ x, short* __restrict__ xb) {
  int idx = blockIdx.x * 256 + threadIdx.x;
  f32x4 v = ((const f32x4*)x)[idx];
  u16x4 o;
  o[0] = (unsigned short)f2bf(v[0]);
  o[1] = (unsigned short)f2bf(v[1]);
  o[2] = (unsigned short)f2bf(v[2]);
  o[3] = (unsigned short)f2bf(v[3]);
  ((u16x4*)xb)[idx] = o;
}

// ---------------------------------------------------------------------------
// Kernel 2: fold LoRA into weights: W'[p] = W_p + B_p @ A_p  (fp32 -> bf16).
// ---------------------------------------------------------------------------
__global__ void fold_w(const float* __restrict__ wq, const float* __restrict__ wk,
                       const float* __restrict__ wv, const float* __restrict__ wo,
                       const float* __restrict__ bq, const float* __restrict__ bk,
                       const float* __restrict__ bv, const float* __restrict__ bo,
                       const float* __restrict__ aq, const float* __restrict__ ak,
                       const float* __restrict__ av, const float* __restrict__ ao,
                       short* __restrict__ out) {
  const int p = blockIdx.y;
  const float* W  = (p == 0) ? wq : (p == 1) ? wk : (p == 2) ? wv : wo;
  const float* Bm = (p == 0) ? bq : (p == 1) ? bk : (p == 2) ? bv : bo;
  const float* A  = (p == 0) ? aq : (p == 1) ? ak : (p == 2) ? av : ao;
  const int idx = blockIdx.x * 256 + threadIdx.x;
  const int n = idx >> 8;
  const int e4 = idx & 255;
  f32x4 acc = ((const f32x4*)(W + (size_t)n * 1024))[e4];
  const float* br = Bm + n * 16;
  #pragma unroll
  for (int r = 0; r < 16; ++r) {
    const f32x4 a4 = ((const f32x4*)(A + (size_t)r * 1024))[e4];
    const float b = br[r];
    acc[0] += b * a4[0];
    acc[1] += b * a4[1];
    acc[2] += b * a4[2];
    acc[3] += b * a4[3];
  }
  u16x4 o;
  o[0] = (unsigned short)f2bf(acc[0]);
  o[1] = (unsigned short)f2bf(acc[1]);
  o[2] = (unsigned short)f2bf(acc[2]);
  o[3] = (unsigned short)f2bf(acc[3]);
  *(u16x4*)(out + (size_t)p * 1048576 + (size_t)idx * 4) = o;
}

// ---------------------------------------------------------------------------
// GEMM core, double-buffered 2-phase: per K-step issue STAGE(kt+1) first,
// then ds_read+MFMA of kt, then one __syncthreads (drains vmcnt+lgkm).
// LDS 64 KB (2 buf x (A+B) x 16 KB).
// ---------------------------------------------------------------------------
__device__ __forceinline__ void gemm_core_db(const short* __restrict__ xrow,
                                             const short* __restrict__ wrow,
                                             short (&As)[2][8192], short (&Bs)[2][8192],
                                             f32x4 (&acc)[4][4]) {
  const int tid = threadIdx.x;
  const int wv = tid >> 6, lane = tid & 63;
  const int wr = wv >> 1, wc = wv & 1;
  const int lrow = lane & 15, lk = lane >> 4;
  const int srow = lane >> 3, sphys = lane & 7;

#define STAGE_G(buf, kt)                                                       \
  {                                                                            \
    _Pragma("unroll")                                                          \
    for (int i = 0; i < 4; ++i) {                                              \
      const int ch = i * 4 + wv;                                               \
      const int row = ch * 8 + srow;                                           \
      const int sl = sphys ^ (row & 7);                                        \
      gload_lds16(xrow + (size_t)row * 1024 + (kt) * 64 + sl * 8, As[buf] + ch * 512); \
      gload_lds16(wrow + (size_t)row * 1024 + (kt) * 64 + sl * 8, Bs[buf] + ch * 512); \
    }                                                                          \
  }

  STAGE_G(0, 0);
  __syncthreads();
  int cur = 0;
  for (int kt = 0; kt < 16; ++kt) {
    if (kt < 15) STAGE_G(cur ^ 1, kt + 1);       // prefetch next K-tile first
    #pragma unroll
    for (int kc = 0; kc < 2; ++kc) {
      bf16x8 af[4], bw[4];
      #pragma unroll
      for (int mi = 0; mi < 4; ++mi) {
        const int row = wr * 64 + mi * 16 + lrow;
        const int slot = (kc * 4 + lk) ^ (row & 7);
        af[mi] = *(const bf16x8*)(As[cur] + row * 64 + slot * 8);
      }
      #pragma unroll
      for (int nj = 0; nj < 4; ++nj) {
        const int row = wc * 64 + nj * 16 + lrow;
        const int slot = (kc * 4 + lk) ^ (row & 7);
        bw[nj] = *(const bf16x8*)(Bs[cur] + row * 64 + slot * 8);
      }
      #pragma unroll
      for (int mi = 0; mi < 4; ++mi)
        #pragma unroll
        for (int nj = 0; nj < 4; ++nj)
          acc[mi][nj] = __builtin_amdgcn_mfma_f32_16x16x32_bf16(af[mi], bw[nj], acc[mi][nj], 0, 0, 0);
    }
    __syncthreads();     // waits prefetch (vmcnt) + all reads of cur done
    cur ^= 1;
  }
#undef STAGE_G
}

// ---------------------------------------------------------------------------
// Kernel 3: merged q/k/v projection, N = 3072 (wb = [q;k;v] row-blocks).
// 1-D grid 768; swizzle: xcd = wg&7 owns bcols [3*xcd, 3*xcd+3), brow-major.
// q scaled by log2(e)/8.  q,k -> [bh][s][d]; v -> [bh][d][s].
// ---------------------------------------------------------------------------
__global__ __launch_bounds__(256)
void gemm_qkv(const short* __restrict__ xb, const short* __restrict__ wb,
              const float* __restrict__ biasq, const float* __restrict__ biask,
              const float* __restrict__ biasv,
              short* __restrict__ qbuf, short* __restrict__ kbuf, short* __restrict__ vtb) {
  __shared__ short As[2][8192];
  __shared__ short Bs[2][8192];
  const int wg = blockIdx.x;              // 0..767
  const int xcd = wg & 7, ix = wg >> 3;   // 96 blocks per XCD
  const int bcol = xcd * 3 + ix % 3;      // 3 W-panels per XCD (768 KB in L2)
  const int brow = ix / 3;                // A-panel reused across the 3 bcols
  const int p = bcol >> 3;                // 0..7 q, 8..15 k, 16..23 v

  const f32x4 fz = {0.f, 0.f, 0.f, 0.f};
  f32x4 acc[4][4];
  #pragma unroll
  for (int a = 0; a < 4; ++a)
    #pragma unroll
    for (int b = 0; b < 4; ++b) acc[a][b] = fz;

  gemm_core_db(xb + (size_t)brow * 128 * 1024,
               wb + (size_t)bcol * 128 * 1024, As, Bs, acc);

  const int tid = threadIdx.x;
  const int wv = tid >> 6, lane = tid & 63;
  const int wr = wv >> 1, wc = wv & 1;
  const int lrow = lane & 15, lk = lane >> 4;
  const float* bias = (p == 0) ? biasq : (p == 1) ? biask : biasv;
  const float oscale = (p == 0) ? 0.18033688f : 1.0f;   // log2(e)/8 into q
  const int c0 = (bcol & 7) * 128;        // col offset within the projection
  float bcv[4];
  #pragma unroll
  for (int nj = 0; nj < 4; ++nj)
    bcv[nj] = bias[c0 + wc * 64 + nj * 16 + lrow];

  #pragma unroll
  for (int mi = 0; mi < 4; ++mi) {
    #pragma unroll
    for (int r = 0; r < 4; ++r) {
      const int gr = brow * 128 + wr * 64 + mi * 16 + lk * 4 + r;   // C/D row
      const int bb = gr >> 10, s = gr & 1023;
      #pragma unroll
      for (int nj = 0; nj < 4; ++nj) {
        const int gc = c0 + wc * 64 + nj * 16 + lrow;               // C/D col
        const float v = (acc[mi][nj][r] + bcv[nj]) * oscale;
        const int h = gc >> 6, d = gc & 63;
        const int bh = bb * 16 + h;
        if (p == 2)
          vtb[((size_t)bh * 64 + d) * 1024 + s] = f2bf(v);
        else
          ((p == 0) ? qbuf : kbuf)[((size_t)bh * 1024 + s) * 64 + d] = f2bf(v);
      }
    }
  }
}

// ---------------------------------------------------------------------------
// Kernel 4: flash attention, swapped 32x32 MFMA form (unchanged from R4).
// ---------------------------------------------------------------------------
__global__ __launch_bounds__(256)
void attn_kernel(const short* __restrict__ qbuf, const short* __restrict__ kbuf,
                 const short* __restrict__ vtb, short* __restrict__ cb) {
  __shared__ short Ks[2][64 * 64];
  __shared__ short Vs[2][64 * 64];
  const int bh = blockIdx.x, qt = blockIdx.y;
  const int tid = threadIdx.x, w = tid >> 6, lane = tid & 63;
  const int l31 = lane & 31, hi = lane >> 5;
  const int srow = lane >> 3, sphys = lane & 7;
  const short* Qp = qbuf + (size_t)bh * 65536;
  const short* Kp = kbuf + (size_t)bh * 65536;
  const short* Vp = vtb + (size_t)bh * 65536;
  const int q0 = qt * 128 + w * 32;

  bf16x8 bq[4];
  #pragma unroll
  for (int kc = 0; kc < 4; ++kc)
    bq[kc] = *(const bf16x8*)(Qp + (size_t)(q0 + l31) * 64 + kc * 16 + hi * 8);

  const f32x16 fz16 = {0.f,0.f,0.f,0.f,0.f,0.f,0.f,0.f,0.f,0.f,0.f,0.f,0.f,0.f,0.f,0.f};
  float m_run = -1e30f, l_run = 0.f;
  f32x16 acc0 = fz16, acc1 = fz16;

  #define STAGE_KV(buf, tt)                                                  \
    {                                                                        \
      const int t0s = (tt) * 64;                                             \
      _Pragma("unroll")                                                      \
      for (int i = 0; i < 2; ++i) {                                          \
        const int ch = i * 4 + w;                                            \
        const int row = ch * 8 + srow;                                       \
        const int sl = sphys ^ (row & 7);                                    \
        gload_lds16(Kp + (size_t)(t0s + row) * 64 + sl * 8, Ks[buf] + ch * 512); \
        gload_lds16(Vp + (size_t)row * 1024 + t0s + sl * 8, Vs[buf] + ch * 512); \
      }                                                                      \
    }

  STAGE_KV(0, 0);
  __syncthreads();

  int cur = 0;
  for (int tt = 0; tt < 16; ++tt) {
    if (tt < 15) STAGE_KV(cur ^ 1, tt + 1);

    f32x16 s0 = fz16, s1 = fz16;
    #pragma unroll
    for (int kc = 0; kc < 4; ++kc) {
      const int slot = (kc * 2 + hi) ^ (l31 & 7);
      const bf16x8 ak0 = *(const bf16x8*)(Ks[cur] + l31 * 64 + slot * 8);
      const bf16x8 ak1 = *(const bf16x8*)(Ks[cur] + (32 + l31) * 64 + slot * 8);
      s0 = __builtin_amdgcn_mfma_f32_32x32x16_bf16(ak0, bq[kc], s0, 0, 0, 0);
      s1 = __builtin_amdgcn_mfma_f32_32x32x16_bf16(ak1, bq[kc], s1, 0, 0, 0);
    }

    float tm = s0[0];
    #pragma unroll
    for (int r = 1; r < 16; ++r) tm = fmaxf(tm, s0[r]);
    #pragma unroll
    for (int r = 0; r < 16; ++r) tm = fmaxf(tm, s1[r]);
    tm = fmaxf(tm, __shfl_xor(tm, 32, 64));
    const float mn = fmaxf(m_run, tm);
    const float alpha = exp2f(m_run - mn);
    m_run = mn;
    float rs = 0.f;
    #pragma unroll
    for (int r = 0; r < 16; ++r) { const float p = exp2f(s0[r] - mn); s0[r] = p; rs += p; }
    #pragma unroll
    for (int r = 0; r < 16; ++r) { const float p = exp2f(s1[r] - mn); s1[r] = p; rs += p; }
    rs += __shfl_xor(rs, 32, 64);
    l_run = l_run * alpha + rs;
    #pragma unroll
    for (int r = 0; r < 16; ++r) { acc0[r] *= alpha; acc1[r] *= alpha; }

    bf16x8 pf[4];
    build_pfrag(s0, pf[0], pf[1]);
    build_pfrag(s1, pf[2], pf[3]);

    #pragma unroll
    for (int kc4 = 0; kc4 < 4; ++kc4) {
      const int slot = (kc4 * 2 + hi) ^ (l31 & 7);
      const bf16x8 av0 = *(const bf16x8*)(Vs[cur] + l31 * 64 + slot * 8);
      const bf16x8 av1 = *(const bf16x8*)(Vs[cur] + (32 + l31) * 64 + slot * 8);
      acc0 = __builtin_amdgcn_mfma_f32_32x32x16_bf16(av0, pf[kc4], acc0, 0, 0, 0);
      acc1 = __builtin_amdgcn_mfma_f32_32x32x16_bf16(av1, pf[kc4], acc1, 0, 0, 0);
    }

    __syncthreads();
    cur ^= 1;
  }

  const int bb = bh >> 4, h = bh & 15;
  const int s = q0 + l31;
  short* crow = cb + (size_t)(bb * 1024 + s) * 1024 + h * 64;
  const float inv = 1.f / l_run;
  #pragma unroll
  for (int rp = 0; rp < 8; ++rp) {
    const int r = rp * 2;
    const int d = (r & 3) + 8 * (r >> 2) + 4 * hi;
    const unsigned p0 = (unsigned)(unsigned short)f2bf(acc0[r] * inv)
                      | ((unsigned)(unsigned short)f2bf(acc0[r + 1] * inv) << 16);
    const unsigned p1 = (unsigned)(unsigned short)f2bf(acc1[r] * inv)
                      | ((unsigned)(unsigned short)f2bf(acc1[r + 1] * inv) << 16);
    *(unsigned*)(crow + d) = p0;
    *(unsigned*)(crow + 32 + d) = p1;
  }
  #undef STAGE_KV
}

// ---------------------------------------------------------------------------
// Kernel 5: o-projection -> fp32 d_out.  Grid (8,32): xcd = wgid%8 = bcol,
// so each XCD keeps its 256 KB W-panel resident.
// ---------------------------------------------------------------------------
__global__ __launch_bounds__(256)
void gemm_o(const short* __restrict__ cb, const short* __restrict__ wo,
            const float* __restrict__ biaso, float* __restrict__ out) {
  __shared__ short As[2][8192];
  __shared__ short Bs[2][8192];
  const int brow = blockIdx.y, bcol = blockIdx.x;
  const f32x4 fz = {0.f, 0.f, 0.f, 0.f};
  f32x4 acc[4][4];
  #pragma unroll
  for (int a = 0; a < 4; ++a)
    #pragma unroll
    for (int b = 0; b < 4; ++b) acc[a][b] = fz;

  gemm_core_db(cb + (size_t)brow * 128 * 1024, wo + (size_t)bcol * 128 * 1024,
               As, Bs, acc);

  const int tid = threadIdx.x;
  const int wv = tid >> 6, lane = tid & 63;
  const int wr = wv >> 1, wc = wv & 1;
  const int lrow = lane & 15, lk = lane >> 4;
  float bcv[4];
  #pragma unroll
  for (int nj = 0; nj < 4; ++nj)
    bcv[nj] = biaso[bcol * 128 + wc * 64 + nj * 16 + lrow];

  #pragma unroll
  for (int mi = 0; mi < 4; ++mi) {
    #pragma unroll
    for (int r = 0; r < 4; ++r) {
      const int gr = brow * 128 + wr * 64 + mi * 16 + lk * 4 + r;
      #pragma unroll
      for (int nj = 0; nj < 4; ++nj) {
        const int gc = bcol * 128 + wc * 64 + nj * 16 + lrow;
        out[(size_t)gr * 1024 + gc] = acc[mi][nj][r] + bcv[nj];
      }
    }
  }
}

// ---------------------------------------------------------------------------
extern "C" void kernel_launch(void* const* d_in, const int* in_sizes, int n_in,
                              void* d_out, int out_size, void* d_ws, size_t ws_size,
                              hipStream_t stream) {
  (void)in_sizes; (void)n_in; (void)out_size; (void)ws_size;
  const float* x   = (const float*)d_in[0];
  const float* qw  = (const float*)d_in[1];
  const float* qb  = (const float*)d_in[2];
  const float* qla = (const float*)d_in[3];
  const float* qlb = (const float*)d_in[4];
  const float* kw  = (const float*)d_in[5];
  const float* kb  = (const float*)d_in[6];
  const float* kla = (const float*)d_in[7];
  const float* klb = (const float*)d_in[8];
  const float* vw  = (const float*)d_in[9];
  const float* vb  = (const float*)d_in[10];
  const float* vla = (const float*)d_in[11];
  const float* vlb = (const float*)d_in[12];
  const float* ow  = (const float*)d_in[13];
  const float* ob  = (const float*)d_in[14];
  const float* ola = (const float*)d_in[15];
  const float* olb = (const float*)d_in[16];

  short* xb   = (short*)d_ws;                         // 4096*1024 bf16 (reused as ctx)
  short* wb   = xb + (size_t)4096 * 1024;             // 4*1024*1024 bf16
  short* qbuf = wb + (size_t)4 * 1024 * 1024;         // 64*1024*64 each
  short* kbuf = qbuf + (size_t)4194304;
  short* vtb  = kbuf + (size_t)4194304;               // total 40 MB

  build_x<<<4096, 256, 0, stream>>>(x, xb);
  fold_w<<<dim3(1024, 4), 256, 0, stream>>>(qw, kw, vw, ow, qlb, klb, vlb, olb,
                                            qla, kla, vla, ola, wb);
  gemm_qkv<<<768, 256, 0, stream>>>(xb, wb, qb, kb, vb, qbuf, kbuf, vtb);
  attn_kernel<<<dim3(64, 8), 256, 0, stream>>>(qbuf, kbuf, vtb, xb);
  gemm_o<<<dim3(8, 32), 256, 0, stream>>>(xb, wb + (size_t)3 * 1024 * 1024, ob, (float*)d_out);
}

// Round 6
// 133.835 us; speedup vs baseline: 2.7680x; 1.0259x over previous
//
#include <hip/hip_runtime.h>
#include <cstdint>

// ---------------------------------------------------------------------------
// LoRA MHA: B=4,S=1024,E=1024,H=16,D=64,R=16.  bf16 MFMA, fp32 accum.
// LoRA folded into the weights: W' = W + B@A (scale=1).
// R6: GEMM K-loop uses depth-2 counted-vmcnt pipeline (T4): 3 LDS buffers,
// raw s_barrier (no drain), s_waitcnt vmcnt(16) so the global_load_lds queue
// never empties; stage of tile kt+2 issued while computing tile kt.
// ---------------------------------------------------------------------------

typedef __attribute__((ext_vector_type(8))) short bf16x8;
typedef __attribute__((ext_vector_type(4))) float f32x4;
typedef __attribute__((ext_vector_type(16))) float f32x16;
typedef __attribute__((ext_vector_type(4))) unsigned short u16x4;
typedef __attribute__((ext_vector_type(4))) unsigned int u32x4;

__device__ __forceinline__ short f2bf(float f) {
  unsigned u = __builtin_bit_cast(unsigned, f);
  u += 0x7FFFu + ((u >> 16) & 1u);          // RNE
  return (short)(u >> 16);
}

typedef __attribute__((address_space(1))) const unsigned int as1_uint;
typedef __attribute__((address_space(3))) unsigned int as3_uint;

__device__ __forceinline__ void gload_lds16(const short* g, const short* l) {
  __builtin_amdgcn_global_load_lds((as1_uint*)g,
      (as3_uint*)(unsigned int)(uintptr_t)l, 16, 0, 0);
}

__device__ __forceinline__ unsigned cvtpk(float lo, float hi) {
  unsigned r;
  asm("v_cvt_pk_bf16_f32 %0, %1, %2" : "=v"(r) : "v"(lo), "v"(hi));
  return r;
}
__device__ __forceinline__ void plswap(unsigned &a, unsigned &b) {
  asm("v_permlane32_swap_b32 %0, %1" : "+v"(a), "+v"(b));
}

__device__ __forceinline__ void build_pfrag(const f32x16 &s, bf16x8 &f0, bf16x8 &f1) {
  unsigned x0 = cvtpk(s[0], s[1]),  x1 = cvtpk(s[2], s[3]);
  unsigned x2 = cvtpk(s[4], s[5]),  x3 = cvtpk(s[6], s[7]);
  plswap(x0, x2); plswap(x1, x3);
  unsigned y0 = cvtpk(s[8], s[9]),  y1 = cvtpk(s[10], s[11]);
  unsigned y2 = cvtpk(s[12], s[13]), y3 = cvtpk(s[14], s[15]);
  plswap(y0, y2); plswap(y1, y3);
  u32x4 a = {x0, x1, x2, x3}, b = {y0, y1, y2, y3};
  f0 = __builtin_bit_cast(bf16x8, a);
  f1 = __builtin_bit_cast(bf16x8, b);
}

// ---------------------------------------------------------------------------
// Kernel 1: cast x (fp32) -> bf16 [4096][1024].
// ---------------------------------------------------------------------------
__global__ void build_x(const float* __restrict__ x, short* __restrict__ xb) {
  int idx = blockIdx.x * 256 + threadIdx.x;
  f32x4 v = ((const f32x4*)x)[idx];
  u16x4 o;
  o[0] = (unsigned short)f2bf(v[0]);
  o[1] = (unsigned short)f2bf(v[1]);
  o[2] = (unsigned short)f2bf(v[2]);
  o[3] = (unsigned short)f2bf(v[3]);
  ((u16x4*)xb)[idx] = o;
}

// ---------------------------------------------------------------------------
// Kernel 2: fold LoRA into weights: W'[p] = W_p + B_p @ A_p  (fp32 -> bf16).
// ---------------------------------------------------------------------------
__global__ void fold_w(const float* __restrict__ wq, const float* __restrict__ wk,
                       const float* __restrict__ wv, const float* __restrict__ wo,
                       const float* __restrict__ bq, const float* __restrict__ bk,
                       const float* __restrict__ bv, const float* __restrict__ bo,
                       const float* __restrict__ aq, const float* __restrict__ ak,
                       const float* __restrict__ av, const float* __restrict__ ao,
                       short* __restrict__ out) {
  const int p = blockIdx.y;
  const float* W  = (p == 0) ? wq : (p == 1) ? wk : (p == 2) ? wv : wo;
  const float* Bm = (p == 0) ? bq : (p == 1) ? bk : (p == 2) ? bv : bo;
  const float* A  = (p == 0) ? aq : (p == 1) ? ak : (p == 2) ? av : ao;
  const int idx = blockIdx.x * 256 + threadIdx.x;
  const int n = idx >> 8;
  const int e4 = idx & 255;
  f32x4 acc = ((const f32x4*)(W + (size_t)n * 1024))[e4];
  const float* br = Bm + n * 16;
  #pragma unroll
  for (int r = 0; r < 16; ++r) {
    const f32x4 a4 = ((const f32x4*)(A + (size_t)r * 1024))[e4];
    const float b = br[r];
    acc[0] += b * a4[0];
    acc[1] += b * a4[1];
    acc[2] += b * a4[2];
    acc[3] += b * a4[3];
  }
  u16x4 o;
  o[0] = (unsigned short)f2bf(acc[0]);
  o[1] = (unsigned short)f2bf(acc[1]);
  o[2] = (unsigned short)f2bf(acc[2]);
  o[3] = (unsigned short)f2bf(acc[3]);
  *(u16x4*)(out + (size_t)p * 1048576 + (size_t)idx * 4) = o;
}

// ---------------------------------------------------------------------------
// GEMM core, depth-2 counted-vmcnt pipeline (T4).  3 LDS buffers (ring).
// Per K-step kt: issue STAGE(kt+2) (8 gload_lds/thread), wait vmcnt(16)
// (= tile kt landed; 2 newer tiles stay in flight), raw barrier, ds_read +
// 32 MFMA, lgkmcnt(0), raw barrier (reads published before slot reuse).
// Invariants: slot (kt+2)%3 last read at step kt-1, whose lgkmcnt(0)+barrier
// precedes this step's stage issue in all waves.
// ---------------------------------------------------------------------------
__device__ __forceinline__ void gemm_core_p3(const short* __restrict__ xrow,
                                             const short* __restrict__ wrow,
                                             short (&As)[3][8192], short (&Bs)[3][8192],
                                             f32x4 (&acc)[4][4]) {
  const int tid = threadIdx.x;
  const int wv = tid >> 6, lane = tid & 63;
  const int wr = wv >> 1, wc = wv & 1;
  const int lrow = lane & 15, lk = lane >> 4;
  const int srow = lane >> 3, sphys = lane & 7;

#define STAGE_G(buf, kt)                                                       \
  {                                                                            \
    _Pragma("unroll")                                                          \
    for (int i = 0; i < 4; ++i) {                                              \
      const int ch = i * 4 + wv;                                               \
      const int row = ch * 8 + srow;                                           \
      const int sl = sphys ^ (row & 7);                                        \
      gload_lds16(xrow + (size_t)row * 1024 + (kt) * 64 + sl * 8, As[buf] + ch * 512); \
      gload_lds16(wrow + (size_t)row * 1024 + (kt) * 64 + sl * 8, Bs[buf] + ch * 512); \
    }                                                                          \
  }

  STAGE_G(0, 0);
  STAGE_G(1, 1);
  int cur = 0;
  for (int kt = 0; kt < 16; ++kt) {
    if (kt < 14) {
      const int nb = (cur == 0) ? 2 : (cur - 1);   // (kt+2)%3
      STAGE_G(nb, kt + 2);
      asm volatile("s_waitcnt vmcnt(16)" ::: "memory");
    } else if (kt == 14) {
      asm volatile("s_waitcnt vmcnt(8)" ::: "memory");
    } else {
      asm volatile("s_waitcnt vmcnt(0)" ::: "memory");
    }
    __builtin_amdgcn_s_barrier();            // tile kt visible to all waves

    #pragma unroll
    for (int kc = 0; kc < 2; ++kc) {
      bf16x8 af[4], bw[4];
      #pragma unroll
      for (int mi = 0; mi < 4; ++mi) {
        const int row = wr * 64 + mi * 16 + lrow;
        const int slot = (kc * 4 + lk) ^ (row & 7);
        af[mi] = *(const bf16x8*)(As[cur] + row * 64 + slot * 8);
      }
      #pragma unroll
      for (int nj = 0; nj < 4; ++nj) {
        const int row = wc * 64 + nj * 16 + lrow;
        const int slot = (kc * 4 + lk) ^ (row & 7);
        bw[nj] = *(const bf16x8*)(Bs[cur] + row * 64 + slot * 8);
      }
      #pragma unroll
      for (int mi = 0; mi < 4; ++mi)
        #pragma unroll
        for (int nj = 0; nj < 4; ++nj)
          acc[mi][nj] = __builtin_amdgcn_mfma_f32_16x16x32_bf16(af[mi], bw[nj], acc[mi][nj], 0, 0, 0);
    }

    asm volatile("s_waitcnt lgkmcnt(0)" ::: "memory");  // my reads of cur done
    __builtin_amdgcn_s_barrier();            // publish: slot may be re-staged
    cur = (cur == 2) ? 0 : (cur + 1);
  }
#undef STAGE_G
}

// ---------------------------------------------------------------------------
// Kernel 3: merged q/k/v projection, N = 3072 (wb = [q;k;v] row-blocks).
// 1-D grid 768; swizzle: xcd = wg&7 owns bcols [3*xcd, 3*xcd+3), brow-major.
// q scaled by log2(e)/8.  q,k -> [bh][s][d]; v -> [bh][d][s].
// ---------------------------------------------------------------------------
__global__ __launch_bounds__(256)
void gemm_qkv(const short* __restrict__ xb, const short* __restrict__ wb,
              const float* __restrict__ biasq, const float* __restrict__ biask,
              const float* __restrict__ biasv,
              short* __restrict__ qbuf, short* __restrict__ kbuf, short* __restrict__ vtb) {
  __shared__ short As[3][8192];
  __shared__ short Bs[3][8192];
  const int wg = blockIdx.x;              // 0..767
  const int xcd = wg & 7, ix = wg >> 3;   // 96 blocks per XCD
  const int bcol = xcd * 3 + ix % 3;      // 3 W-panels per XCD (768 KB in L2)
  const int brow = ix / 3;                // A-panel reused across the 3 bcols
  const int p = bcol >> 3;                // 0..7 q, 8..15 k, 16..23 v

  const f32x4 fz = {0.f, 0.f, 0.f, 0.f};
  f32x4 acc[4][4];
  #pragma unroll
  for (int a = 0; a < 4; ++a)
    #pragma unroll
    for (int b = 0; b < 4; ++b) acc[a][b] = fz;

  gemm_core_p3(xb + (size_t)brow * 128 * 1024,
               wb + (size_t)bcol * 128 * 1024, As, Bs, acc);

  const int tid = threadIdx.x;
  const int wv = tid >> 6, lane = tid & 63;
  const int wr = wv >> 1, wc = wv & 1;
  const int lrow = lane & 15, lk = lane >> 4;
  const float* bias = (p == 0) ? biasq : (p == 1) ? biask : biasv;
  const float oscale = (p == 0) ? 0.18033688f : 1.0f;   // log2(e)/8 into q
  const int c0 = (bcol & 7) * 128;        // col offset within the projection
  float bcv[4];
  #pragma unroll
  for (int nj = 0; nj < 4; ++nj)
    bcv[nj] = bias[c0 + wc * 64 + nj * 16 + lrow];

  #pragma unroll
  for (int mi = 0; mi < 4; ++mi) {
    #pragma unroll
    for (int r = 0; r < 4; ++r) {
      const int gr = brow * 128 + wr * 64 + mi * 16 + lk * 4 + r;   // C/D row
      const int bb = gr >> 10, s = gr & 1023;
      #pragma unroll
      for (int nj = 0; nj < 4; ++nj) {
        const int gc = c0 + wc * 64 + nj * 16 + lrow;               // C/D col
        const float v = (acc[mi][nj][r] + bcv[nj]) * oscale;
        const int h = gc >> 6, d = gc & 63;
        const int bh = bb * 16 + h;
        if (p == 2)
          vtb[((size_t)bh * 64 + d) * 1024 + s] = f2bf(v);
        else
          ((p == 0) ? qbuf : kbuf)[((size_t)bh * 1024 + s) * 64 + d] = f2bf(v);
      }
    }
  }
}

// ---------------------------------------------------------------------------
// Kernel 4: flash attention, swapped 32x32 MFMA form (unchanged from R5).
// ---------------------------------------------------------------------------
__global__ __launch_bounds__(256)
void attn_kernel(const short* __restrict__ qbuf, const short* __restrict__ kbuf,
                 const short* __restrict__ vtb, short* __restrict__ cb) {
  __shared__ short Ks[2][64 * 64];
  __shared__ short Vs[2][64 * 64];
  const int bh = blockIdx.x, qt = blockIdx.y;
  const int tid = threadIdx.x, w = tid >> 6, lane = tid & 63;
  const int l31 = lane & 31, hi = lane >> 5;
  const int srow = lane >> 3, sphys = lane & 7;
  const short* Qp = qbuf + (size_t)bh * 65536;
  const short* Kp = kbuf + (size_t)bh * 65536;
  const short* Vp = vtb + (size_t)bh * 65536;
  const int q0 = qt * 128 + w * 32;

  bf16x8 bq[4];
  #pragma unroll
  for (int kc = 0; kc < 4; ++kc)
    bq[kc] = *(const bf16x8*)(Qp + (size_t)(q0 + l31) * 64 + kc * 16 + hi * 8);

  const f32x16 fz16 = {0.f,0.f,0.f,0.f,0.f,0.f,0.f,0.f,0.f,0.f,0.f,0.f,0.f,0.f,0.f,0.f};
  float m_run = -1e30f, l_run = 0.f;
  f32x16 acc0 = fz16, acc1 = fz16;

  #define STAGE_KV(buf, tt)                                                  \
    {                                                                        \
      const int t0s = (tt) * 64;                                             \
      _Pragma("unroll")                                                      \
      for (int i = 0; i < 2; ++i) {                                          \
        const int ch = i * 4 + w;                                            \
        const int row = ch * 8 + srow;                                       \
        const int sl = sphys ^ (row & 7);                                    \
        gload_lds16(Kp + (size_t)(t0s + row) * 64 + sl * 8, Ks[buf] + ch * 512); \
        gload_lds16(Vp + (size_t)row * 1024 + t0s + sl * 8, Vs[buf] + ch * 512); \
      }                                                                      \
    }

  STAGE_KV(0, 0);
  __syncthreads();

  int cur = 0;
  for (int tt = 0; tt < 16; ++tt) {
    if (tt < 15) STAGE_KV(cur ^ 1, tt + 1);

    f32x16 s0 = fz16, s1 = fz16;
    #pragma unroll
    for (int kc = 0; kc < 4; ++kc) {
      const int slot = (kc * 2 + hi) ^ (l31 & 7);
      const bf16x8 ak0 = *(const bf16x8*)(Ks[cur] + l31 * 64 + slot * 8);
      const bf16x8 ak1 = *(const bf16x8*)(Ks[cur] + (32 + l31) * 64 + slot * 8);
      s0 = __builtin_amdgcn_mfma_f32_32x32x16_bf16(ak0, bq[kc], s0, 0, 0, 0);
      s1 = __builtin_amdgcn_mfma_f32_32x32x16_bf16(ak1, bq[kc], s1, 0, 0, 0);
    }

    float tm = s0[0];
    #pragma unroll
    for (int r = 1; r < 16; ++r) tm = fmaxf(tm, s0[r]);
    #pragma unroll
    for (int r = 0; r < 16; ++r) tm = fmaxf(tm, s1[r]);
    tm = fmaxf(tm, __shfl_xor(tm, 32, 64));
    const float mn = fmaxf(m_run, tm);
    const float alpha = exp2f(m_run - mn);
    m_run = mn;
    float rs = 0.f;
    #pragma unroll
    for (int r = 0; r < 16; ++r) { const float p = exp2f(s0[r] - mn); s0[r] = p; rs += p; }
    #pragma unroll
    for (int r = 0; r < 16; ++r) { const float p = exp2f(s1[r] - mn); s1[r] = p; rs += p; }
    rs += __shfl_xor(rs, 32, 64);
    l_run = l_run * alpha + rs;
    #pragma unroll
    for (int r = 0; r < 16; ++r) { acc0[r] *= alpha; acc1[r] *= alpha; }

    bf16x8 pf[4];
    build_pfrag(s0, pf[0], pf[1]);
    build_pfrag(s1, pf[2], pf[3]);

    #pragma unroll
    for (int kc4 = 0; kc4 < 4; ++kc4) {
      const int slot = (kc4 * 2 + hi) ^ (l31 & 7);
      const bf16x8 av0 = *(const bf16x8*)(Vs[cur] + l31 * 64 + slot * 8);
      const bf16x8 av1 = *(const bf16x8*)(Vs[cur] + (32 + l31) * 64 + slot * 8);
      acc0 = __builtin_amdgcn_mfma_f32_32x32x16_bf16(av0, pf[kc4], acc0, 0, 0, 0);
      acc1 = __builtin_amdgcn_mfma_f32_32x32x16_bf16(av1, pf[kc4], acc1, 0, 0, 0);
    }

    __syncthreads();
    cur ^= 1;
  }

  const int bb = bh >> 4, h = bh & 15;
  const int s = q0 + l31;
  short* crow = cb + (size_t)(bb * 1024 + s) * 1024 + h * 64;
  const float inv = 1.f / l_run;
  #pragma unroll
  for (int rp = 0; rp < 8; ++rp) {
    const int r = rp * 2;
    const int d = (r & 3) + 8 * (r >> 2) + 4 * hi;
    const unsigned p0 = (unsigned)(unsigned short)f2bf(acc0[r] * inv)
                      | ((unsigned)(unsigned short)f2bf(acc0[r + 1] * inv) << 16);
    const unsigned p1 = (unsigned)(unsigned short)f2bf(acc1[r] * inv)
                      | ((unsigned)(unsigned short)f2bf(acc1[r + 1] * inv) << 16);
    *(unsigned*)(crow + d) = p0;
    *(unsigned*)(crow + 32 + d) = p1;
  }
  #undef STAGE_KV
}

// ---------------------------------------------------------------------------
// Kernel 5: o-projection -> fp32 d_out.  Grid (8,32): xcd = wgid%8 = bcol,
// so each XCD keeps its 256 KB W-panel resident.
// ---------------------------------------------------------------------------
__global__ __launch_bounds__(256)
void gemm_o(const short* __restrict__ cb, const short* __restrict__ wo,
            const float* __restrict__ biaso, float* __restrict__ out) {
  __shared__ short As[3][8192];
  __shared__ short Bs[3][8192];
  const int brow = blockIdx.y, bcol = blockIdx.x;
  const f32x4 fz = {0.f, 0.f, 0.f, 0.f};
  f32x4 acc[4][4];
  #pragma unroll
  for (int a = 0; a < 4; ++a)
    #pragma unroll
    for (int b = 0; b < 4; ++b) acc[a][b] = fz;

  gemm_core_p3(cb + (size_t)brow * 128 * 1024, wo + (size_t)bcol * 128 * 1024,
               As, Bs, acc);

  const int tid = threadIdx.x;
  const int wv = tid >> 6, lane = tid & 63;
  const int wr = wv >> 1, wc = wv & 1;
  const int lrow = lane & 15, lk = lane >> 4;
  float bcv[4];
  #pragma unroll
  for (int nj = 0; nj < 4; ++nj)
    bcv[nj] = biaso[bcol * 128 + wc * 64 + nj * 16 + lrow];

  #pragma unroll
  for (int mi = 0; mi < 4; ++mi) {
    #pragma unroll
    for (int r = 0; r < 4; ++r) {
      const int gr = brow * 128 + wr * 64 + mi * 16 + lk * 4 + r;
      #pragma unroll
      for (int nj = 0; nj < 4; ++nj) {
        const int gc = bcol * 128 + wc * 64 + nj * 16 + lrow;
        out[(size_t)gr * 1024 + gc] = acc[mi][nj][r] + bcv[nj];
      }
    }
  }
}

// ---------------------------------------------------------------------------
extern "C" void kernel_launch(void* const* d_in, const int* in_sizes, int n_in,
                              void* d_out, int out_size, void* d_ws, size_t ws_size,
                              hipStream_t stream) {
  (void)in_sizes; (void)n_in; (void)out_size; (void)ws_size;
  const float* x   = (const float*)d_in[0];
  const float* qw  = (const float*)d_in[1];
  const float* qb  = (const float*)d_in[2];
  const float* qla = (const float*)d_in[3];
  const float* qlb = (const float*)d_in[4];
  const float* kw  = (const float*)d_in[5];
  const float* kb  = (const float*)d_in[6];
  const float* kla = (const float*)d_in[7];
  const float* klb = (const float*)d_in[8];
  const float* vw  = (const float*)d_in[9];
  const float* vb  = (const float*)d_in[10];
  const float* vla = (const float*)d_in[11];
  const float* vlb = (const float*)d_in[12];
  const float* ow  = (const float*)d_in[13];
  const float* ob  = (const float*)d_in[14];
  const float* ola = (const float*)d_in[15];
  const float* olb = (const float*)d_in[16];

  short* xb   = (short*)d_ws;                         // 4096*1024 bf16 (reused as ctx)
  short* wb   = xb + (size_t)4096 * 1024;             // 4*1024*1024 bf16
  short* qbuf = wb + (size_t)4 * 1024 * 1024;         // 64*1024*64 each
  short* kbuf = qbuf + (size_t)4194304;
  short* vtb  = kbuf + (size_t)4194304;               // total 40 MB

  build_x<<<4096, 256, 0, stream>>>(x, xb);
  fold_w<<<dim3(1024, 4), 256, 0, stream>>>(qw, kw, vw, ow, qlb, klb, vlb, olb,
                                            qla, kla, vla, ola, wb);
  gemm_qkv<<<768, 256, 0, stream>>>(xb, wb, qb, kb, vb, qbuf, kbuf, vtb);
  attn_kernel<<<dim3(64, 8), 256, 0, stream>>>(qbuf, kbuf, vtb, xb);
  gemm_o<<<dim3(8, 32), 256, 0, stream>>>(xb, wb + (size_t)3 * 1024 * 1024, ob, (float*)d_out);
}

// Round 7
// 132.355 us; speedup vs baseline: 2.7990x; 1.0112x over previous
//
#include <hip/hip_runtime.h>
#include <cstdint>

// ---------------------------------------------------------------------------
// LoRA MHA: B=4,S=1024,E=1024,H=16,D=64,R=16.  bf16 MFMA, fp32 accum.
// LoRA folded into the weights: W' = W + B@A (scale=1).
// R7: gemm_qkv rewritten as 256x256-tile 8-wave quadrant-pipelined kernel:
// per K-tile, 4 phases of {stage-half(kt+1) || A-frag ds_read || setprio'd
// 16-MFMA cluster}; B-frags register-held per K-tile; one vmcnt+barrier per
// K-tile (loads awaited were issued a full iteration earlier).
// ---------------------------------------------------------------------------

typedef __attribute__((ext_vector_type(8))) short bf16x8;
typedef __attribute__((ext_vector_type(4))) float f32x4;
typedef __attribute__((ext_vector_type(16))) float f32x16;
typedef __attribute__((ext_vector_type(4))) unsigned short u16x4;
typedef __attribute__((ext_vector_type(4))) unsigned int u32x4;

__device__ __forceinline__ short f2bf(float f) {
  unsigned u = __builtin_bit_cast(unsigned, f);
  u += 0x7FFFu + ((u >> 16) & 1u);          // RNE
  return (short)(u >> 16);
}

typedef __attribute__((address_space(1))) const unsigned int as1_uint;
typedef __attribute__((address_space(3))) unsigned int as3_uint;

__device__ __forceinline__ void gload_lds16(const short* g, const short* l) {
  __builtin_amdgcn_global_load_lds((as1_uint*)g,
      (as3_uint*)(unsigned int)(uintptr_t)l, 16, 0, 0);
}

__device__ __forceinline__ unsigned cvtpk(float lo, float hi) {
  unsigned r;
  asm("v_cvt_pk_bf16_f32 %0, %1, %2" : "=v"(r) : "v"(lo), "v"(hi));
  return r;
}
__device__ __forceinline__ void plswap(unsigned &a, unsigned &b) {
  asm("v_permlane32_swap_b32 %0, %1" : "+v"(a), "+v"(b));
}

__device__ __forceinline__ void build_pfrag(const f32x16 &s, bf16x8 &f0, bf16x8 &f1) {
  unsigned x0 = cvtpk(s[0], s[1]),  x1 = cvtpk(s[2], s[3]);
  unsigned x2 = cvtpk(s[4], s[5]),  x3 = cvtpk(s[6], s[7]);
  plswap(x0, x2); plswap(x1, x3);
  unsigned y0 = cvtpk(s[8], s[9]),  y1 = cvtpk(s[10], s[11]);
  unsigned y2 = cvtpk(s[12], s[13]), y3 = cvtpk(s[14], s[15]);
  plswap(y0, y2); plswap(y1, y3);
  u32x4 a = {x0, x1, x2, x3}, b = {y0, y1, y2, y3};
  f0 = __builtin_bit_cast(bf16x8, a);
  f1 = __builtin_bit_cast(bf16x8, b);
}

// ---------------------------------------------------------------------------
// Kernel 1: cast x (fp32) -> bf16 [4096][1024].
// ---------------------------------------------------------------------------
__global__ void build_x(const float* __restrict__ x, short* __restrict__ xb) {
  int idx = blockIdx.x * 256 + threadIdx.x;
  f32x4 v = ((const f32x4*)x)[idx];
  u16x4 o;
  o[0] = (unsigned short)f2bf(v[0]);
  o[1] = (unsigned short)f2bf(v[1]);
  o[2] = (unsigned short)f2bf(v[2]);
  o[3] = (unsigned short)f2bf(v[3]);
  ((u16x4*)xb)[idx] = o;
}

// ---------------------------------------------------------------------------
// Kernel 2: fold LoRA into weights: W'[p] = W_p + B_p @ A_p  (fp32 -> bf16).
// ---------------------------------------------------------------------------
__global__ void fold_w(const float* __restrict__ wq, const float* __restrict__ wk,
                       const float* __restrict__ wv, const float* __restrict__ wo,
                       const float* __restrict__ bq, const float* __restrict__ bk,
                       const float* __restrict__ bv, const float* __restrict__ bo,
                       const float* __restrict__ aq, const float* __restrict__ ak,
                       const float* __restrict__ av, const float* __restrict__ ao,
                       short* __restrict__ out) {
  const int p = blockIdx.y;
  const float* W  = (p == 0) ? wq : (p == 1) ? wk : (p == 2) ? wv : wo;
  const float* Bm = (p == 0) ? bq : (p == 1) ? bk : (p == 2) ? bv : bo;
  const float* A  = (p == 0) ? aq : (p == 1) ? ak : (p == 2) ? av : ao;
  const int idx = blockIdx.x * 256 + threadIdx.x;
  const int n = idx >> 8;
  const int e4 = idx & 255;
  f32x4 acc = ((const f32x4*)(W + (size_t)n * 1024))[e4];
  const float* br = Bm + n * 16;
  #pragma unroll
  for (int r = 0; r < 16; ++r) {
    const f32x4 a4 = ((const f32x4*)(A + (size_t)r * 1024))[e4];
    const float b = br[r];
    acc[0] += b * a4[0];
    acc[1] += b * a4[1];
    acc[2] += b * a4[2];
    acc[3] += b * a4[3];
  }
  u16x4 o;
  o[0] = (unsigned short)f2bf(acc[0]);
  o[1] = (unsigned short)f2bf(acc[1]);
  o[2] = (unsigned short)f2bf(acc[2]);
  o[3] = (unsigned short)f2bf(acc[3]);
  *(u16x4*)(out + (size_t)p * 1048576 + (size_t)idx * 4) = o;
}

// ---------------------------------------------------------------------------
// Kernel 3: merged q/k/v projection, 256x256 tile, 8 waves (2M x 4N).
// Grid 192 = 16 brow x 12 bcol; swz: XCD owns 2 brows x all 12 bcols.
// Schedule per K-tile kt (16 total):
//   vmcnt(0)+lgkmcnt(0)+s_barrier   (kt's halves landed; buf^1 free)
//   B-frags: 8 ds_read_b128 (held for whole K-tile)
//   4 quadrant phases: stage half q of kt+1 -> buf^1 (2 gload_lds),
//                      4 A-frag ds_reads, setprio(1), 16 MFMA, setprio(0)
// Hazards: reads only buf[cur]; writes only buf[cur^1], whose readers all
// passed the entry barrier.  One barrier per K-tile.
// ---------------------------------------------------------------------------
__global__ __launch_bounds__(512)
void gemm_qkv(const short* __restrict__ xb, const short* __restrict__ wb,
              const float* __restrict__ biasq, const float* __restrict__ biask,
              const float* __restrict__ biasv,
              short* __restrict__ qbuf, short* __restrict__ kbuf, short* __restrict__ vtb) {
  __shared__ short Ah[2][2][8192];     // [buf][half][128*64]
  __shared__ short Bh[2][2][8192];
  const int wg = blockIdx.x;                   // 0..191
  const int swz = (wg & 7) * 24 + (wg >> 3);   // bijective XCD transpose
  const int brow = swz / 12, bcol = swz % 12;
  const int tid = threadIdx.x;
  const int wid = tid >> 6, lane = tid & 63;
  const int wr = wid >> 2, wc = wid & 3;       // 2M x 4N wave grid
  const int lrow = lane & 15, lk = lane >> 4;
  const int l8 = lane & 7, lh = lane >> 3;
  const int sl = l8 ^ lh;                      // inverse-swizzled source slot

  const short* Arow = xb + (size_t)brow * 256 * 1024;
  const short* Brow = wb + (size_t)bcol * 256 * 1024;

#define STAGE_H(DST, SRC, hf, buf, kt)                                         \
  { _Pragma("unroll")                                                          \
    for (int i = 0; i < 2; ++i) {                                              \
      gload_lds16((SRC) + (size_t)((hf) * 128 + (i * 8 + wid) * 8 + lh) * 1024 \
                        + (kt) * 64 + sl * 8,                                  \
                  &DST[buf][hf][(i * 8 + wid) * 512]);                         \
    } }

  const f32x4 fz = {0.f, 0.f, 0.f, 0.f};
  f32x4 acc[8][4];
  #pragma unroll
  for (int a = 0; a < 8; ++a)
    #pragma unroll
    for (int b = 0; b < 4; ++b) acc[a][b] = fz;

  // prologue: K-tile 0 -> buf 0
  STAGE_H(Ah, Arow, 0, 0, 0)
  STAGE_H(Ah, Arow, 1, 0, 0)
  STAGE_H(Bh, Brow, 0, 0, 0)
  STAGE_H(Bh, Brow, 1, 0, 0)

  const int bhalf = wc >> 1;
  for (int kt = 0; kt < 16; ++kt) {
    const int cur = kt & 1;
    asm volatile("s_waitcnt vmcnt(0)" ::: "memory");
    asm volatile("s_waitcnt lgkmcnt(0)" ::: "memory");
    __builtin_amdgcn_s_barrier();

    // B-frags for the whole K-tile (held in registers)
    bf16x8 bfr[4][2];
    #pragma unroll
    for (int nj = 0; nj < 4; ++nj) {
      const int rr = (wc & 1) * 64 + nj * 16 + lrow;
      #pragma unroll
      for (int kc = 0; kc < 2; ++kc)
        bfr[nj][kc] = *(const bf16x8*)(&Bh[cur][bhalf][rr * 64 + (((kc * 4 + lk) ^ (lrow & 7)) * 8)]);
    }

    #pragma unroll
    for (int q = 0; q < 4; ++q) {
      if (kt < 15) {
        if (q == 0)      STAGE_H(Ah, Arow, 0, cur ^ 1, kt + 1)
        else if (q == 1) STAGE_H(Ah, Arow, 1, cur ^ 1, kt + 1)
        else if (q == 2) STAGE_H(Bh, Brow, 0, cur ^ 1, kt + 1)
        else             STAGE_H(Bh, Brow, 1, cur ^ 1, kt + 1)
      }
      bf16x8 afr[2][2];
      #pragma unroll
      for (int m2 = 0; m2 < 2; ++m2) {
        const int rr = (q * 2 + m2) * 16 + lrow;
        #pragma unroll
        for (int kc = 0; kc < 2; ++kc)
          afr[m2][kc] = *(const bf16x8*)(&Ah[cur][wr][rr * 64 + (((kc * 4 + lk) ^ (lrow & 7)) * 8)]);
      }
      __builtin_amdgcn_s_setprio(1);
      #pragma unroll
      for (int kc = 0; kc < 2; ++kc)
        #pragma unroll
        for (int m2 = 0; m2 < 2; ++m2)
          #pragma unroll
          for (int nj = 0; nj < 4; ++nj)
            acc[q * 2 + m2][nj] = __builtin_amdgcn_mfma_f32_16x16x32_bf16(
                afr[m2][kc], bfr[nj][kc], acc[q * 2 + m2][nj], 0, 0, 0);
      __builtin_amdgcn_s_setprio(0);
    }
  }
#undef STAGE_H

  // epilogue: p uniform per block (bcol/4); q scaled by log2(e)/8
  const int p = bcol >> 2;
  const float* bias = (p == 0) ? biasq : (p == 1) ? biask : biasv;
  const float oscale = (p == 0) ? 0.18033688f : 1.0f;
  const int c0 = (bcol & 3) * 256 + wc * 64;
  float bcv[4];
  #pragma unroll
  for (int nj = 0; nj < 4; ++nj)
    bcv[nj] = bias[c0 + nj * 16 + lrow];

  #pragma unroll
  for (int mi = 0; mi < 8; ++mi) {
    #pragma unroll
    for (int r = 0; r < 4; ++r) {
      const int gr = brow * 256 + wr * 128 + mi * 16 + lk * 4 + r;   // C/D row
      const int bb = gr >> 10, s = gr & 1023;
      #pragma unroll
      for (int nj = 0; nj < 4; ++nj) {
        const int gc = c0 + nj * 16 + lrow;                          // 0..1023
        const float v = (acc[mi][nj][r] + bcv[nj]) * oscale;
        const int h = gc >> 6, d = gc & 63;
        const int bh = bb * 16 + h;
        if (p == 2)
          vtb[((size_t)bh * 64 + d) * 1024 + s] = f2bf(v);
        else
          ((p == 0) ? qbuf : kbuf)[((size_t)bh * 1024 + s) * 64 + d] = f2bf(v);
      }
    }
  }
}

// ---------------------------------------------------------------------------
// GEMM core, depth-2 counted-vmcnt pipeline (kept for gemm_o: 1 block/CU
// grid where the deep pipeline helped in R6).  3 LDS buffers (ring).
// ---------------------------------------------------------------------------
__device__ __forceinline__ void gemm_core_p3(const short* __restrict__ xrow,
                                             const short* __restrict__ wrow,
                                             short (&As)[3][8192], short (&Bs)[3][8192],
                                             f32x4 (&acc)[4][4]) {
  const int tid = threadIdx.x;
  const int wv = tid >> 6, lane = tid & 63;
  const int wr = wv >> 1, wc = wv & 1;
  const int lrow = lane & 15, lk = lane >> 4;
  const int srow = lane >> 3, sphys = lane & 7;

#define STAGE_G(buf, kt)                                                       \
  {                                                                            \
    _Pragma("unroll")                                                          \
    for (int i = 0; i < 4; ++i) {                                              \
      const int ch = i * 4 + wv;                                               \
      const int row = ch * 8 + srow;                                           \
      const int sl = sphys ^ (row & 7);                                        \
      gload_lds16(xrow + (size_t)row * 1024 + (kt) * 64 + sl * 8, As[buf] + ch * 512); \
      gload_lds16(wrow + (size_t)row * 1024 + (kt) * 64 + sl * 8, Bs[buf] + ch * 512); \
    }                                                                          \
  }

  STAGE_G(0, 0);
  STAGE_G(1, 1);
  int cur = 0;
  for (int kt = 0; kt < 16; ++kt) {
    if (kt < 14) {
      const int nb = (cur == 0) ? 2 : (cur - 1);   // (kt+2)%3
      STAGE_G(nb, kt + 2);
      asm volatile("s_waitcnt vmcnt(16)" ::: "memory");
    } else if (kt == 14) {
      asm volatile("s_waitcnt vmcnt(8)" ::: "memory");
    } else {
      asm volatile("s_waitcnt vmcnt(0)" ::: "memory");
    }
    __builtin_amdgcn_s_barrier();

    #pragma unroll
    for (int kc = 0; kc < 2; ++kc) {
      bf16x8 af[4], bw[4];
      #pragma unroll
      for (int mi = 0; mi < 4; ++mi) {
        const int row = wr * 64 + mi * 16 + lrow;
        const int slot = (kc * 4 + lk) ^ (row & 7);
        af[mi] = *(const bf16x8*)(As[cur] + row * 64 + slot * 8);
      }
      #pragma unroll
      for (int nj = 0; nj < 4; ++nj) {
        const int row = wc * 64 + nj * 16 + lrow;
        const int slot = (kc * 4 + lk) ^ (row & 7);
        bw[nj] = *(const bf16x8*)(Bs[cur] + row * 64 + slot * 8);
      }
      #pragma unroll
      for (int mi = 0; mi < 4; ++mi)
        #pragma unroll
        for (int nj = 0; nj < 4; ++nj)
          acc[mi][nj] = __builtin_amdgcn_mfma_f32_16x16x32_bf16(af[mi], bw[nj], acc[mi][nj], 0, 0, 0);
    }

    asm volatile("s_waitcnt lgkmcnt(0)" ::: "memory");
    __builtin_amdgcn_s_barrier();
    cur = (cur == 2) ? 0 : (cur + 1);
  }
#undef STAGE_G
}

// ---------------------------------------------------------------------------
// Kernel 4: flash attention, swapped 32x32 MFMA form (unchanged).
// ---------------------------------------------------------------------------
__global__ __launch_bounds__(256)
void attn_kernel(const short* __restrict__ qbuf, const short* __restrict__ kbuf,
                 const short* __restrict__ vtb, short* __restrict__ cb) {
  __shared__ short Ks[2][64 * 64];
  __shared__ short Vs[2][64 * 64];
  const int bh = blockIdx.x, qt = blockIdx.y;
  const int tid = threadIdx.x, w = tid >> 6, lane = tid & 63;
  const int l31 = lane & 31, hi = lane >> 5;
  const int srow = lane >> 3, sphys = lane & 7;
  const short* Qp = qbuf + (size_t)bh * 65536;
  const short* Kp = kbuf + (size_t)bh * 65536;
  const short* Vp = vtb + (size_t)bh * 65536;
  const int q0 = qt * 128 + w * 32;

  bf16x8 bq[4];
  #pragma unroll
  for (int kc = 0; kc < 4; ++kc)
    bq[kc] = *(const bf16x8*)(Qp + (size_t)(q0 + l31) * 64 + kc * 16 + hi * 8);

  const f32x16 fz16 = {0.f,0.f,0.f,0.f,0.f,0.f,0.f,0.f,0.f,0.f,0.f,0.f,0.f,0.f,0.f,0.f};
  float m_run = -1e30f, l_run = 0.f;
  f32x16 acc0 = fz16, acc1 = fz16;

  #define STAGE_KV(buf, tt)                                                  \
    {                                                                        \
      const int t0s = (tt) * 64;                                             \
      _Pragma("unroll")                                                      \
      for (int i = 0; i < 2; ++i) {                                          \
        const int ch = i * 4 + w;                                            \
        const int row = ch * 8 + srow;                                       \
        const int sl = sphys ^ (row & 7);                                    \
        gload_lds16(Kp + (size_t)(t0s + row) * 64 + sl * 8, Ks[buf] + ch * 512); \
        gload_lds16(Vp + (size_t)row * 1024 + t0s + sl * 8, Vs[buf] + ch * 512); \
      }                                                                      \
    }

  STAGE_KV(0, 0);
  __syncthreads();

  int cur = 0;
  for (int tt = 0; tt < 16; ++tt) {
    if (tt < 15) STAGE_KV(cur ^ 1, tt + 1);

    f32x16 s0 = fz16, s1 = fz16;
    #pragma unroll
    for (int kc = 0; kc < 4; ++kc) {
      const int slot = (kc * 2 + hi) ^ (l31 & 7);
      const bf16x8 ak0 = *(const bf16x8*)(Ks[cur] + l31 * 64 + slot * 8);
      const bf16x8 ak1 = *(const bf16x8*)(Ks[cur] + (32 + l31) * 64 + slot * 8);
      s0 = __builtin_amdgcn_mfma_f32_32x32x16_bf16(ak0, bq[kc], s0, 0, 0, 0);
      s1 = __builtin_amdgcn_mfma_f32_32x32x16_bf16(ak1, bq[kc], s1, 0, 0, 0);
    }

    float tm = s0[0];
    #pragma unroll
    for (int r = 1; r < 16; ++r) tm = fmaxf(tm, s0[r]);
    #pragma unroll
    for (int r = 0; r < 16; ++r) tm = fmaxf(tm, s1[r]);
    tm = fmaxf(tm, __shfl_xor(tm, 32, 64));
    const float mn = fmaxf(m_run, tm);
    const float alpha = exp2f(m_run - mn);
    m_run = mn;
    float rs = 0.f;
    #pragma unroll
    for (int r = 0; r < 16; ++r) { const float p = exp2f(s0[r] - mn); s0[r] = p; rs += p; }
    #pragma unroll
    for (int r = 0; r < 16; ++r) { const float p = exp2f(s1[r] - mn); s1[r] = p; rs += p; }
    rs += __shfl_xor(rs, 32, 64);
    l_run = l_run * alpha + rs;
    #pragma unroll
    for (int r = 0; r < 16; ++r) { acc0[r] *= alpha; acc1[r] *= alpha; }

    bf16x8 pf[4];
    build_pfrag(s0, pf[0], pf[1]);
    build_pfrag(s1, pf[2], pf[3]);

    #pragma unroll
    for (int kc4 = 0; kc4 < 4; ++kc4) {
      const int slot = (kc4 * 2 + hi) ^ (l31 & 7);
      const bf16x8 av0 = *(const bf16x8*)(Vs[cur] + l31 * 64 + slot * 8);
      const bf16x8 av1 = *(const bf16x8*)(Vs[cur] + (32 + l31) * 64 + slot * 8);
      acc0 = __builtin_amdgcn_mfma_f32_32x32x16_bf16(av0, pf[kc4], acc0, 0, 0, 0);
      acc1 = __builtin_amdgcn_mfma_f32_32x32x16_bf16(av1, pf[kc4], acc1, 0, 0, 0);
    }

    __syncthreads();
    cur ^= 1;
  }

  const int bb = bh >> 4, h = bh & 15;
  const int s = q0 + l31;
  short* crow = cb + (size_t)(bb * 1024 + s) * 1024 + h * 64;
  const float inv = 1.f / l_run;
  #pragma unroll
  for (int rp = 0; rp < 8; ++rp) {
    const int r = rp * 2;
    const int d = (r & 3) + 8 * (r >> 2) + 4 * hi;
    const unsigned p0 = (unsigned)(unsigned short)f2bf(acc0[r] * inv)
                      | ((unsigned)(unsigned short)f2bf(acc0[r + 1] * inv) << 16);
    const unsigned p1 = (unsigned)(unsigned short)f2bf(acc1[r] * inv)
                      | ((unsigned)(unsigned short)f2bf(acc1[r + 1] * inv) << 16);
    *(unsigned*)(crow + d) = p0;
    *(unsigned*)(crow + 32 + d) = p1;
  }
  #undef STAGE_KV
}

// ---------------------------------------------------------------------------
// Kernel 5: o-projection -> fp32 d_out (p3 core, grid 256 = 1/CU).
// ---------------------------------------------------------------------------
__global__ __launch_bounds__(256)
void gemm_o(const short* __restrict__ cb, const short* __restrict__ wo,
            const float* __restrict__ biaso, float* __restrict__ out) {
  __shared__ short As[3][8192];
  __shared__ short Bs[3][8192];
  const int brow = blockIdx.y, bcol = blockIdx.x;
  const f32x4 fz = {0.f, 0.f, 0.f, 0.f};
  f32x4 acc[4][4];
  #pragma unroll
  for (int a = 0; a < 4; ++a)
    #pragma unroll
    for (int b = 0; b < 4; ++b) acc[a][b] = fz;

  gemm_core_p3(cb + (size_t)brow * 128 * 1024, wo + (size_t)bcol * 128 * 1024,
               As, Bs, acc);

  const int tid = threadIdx.x;
  const int wv = tid >> 6, lane = tid & 63;
  const int wr = wv >> 1, wc = wv & 1;
  const int lrow = lane & 15, lk = lane >> 4;
  float bcv[4];
  #pragma unroll
  for (int nj = 0; nj < 4; ++nj)
    bcv[nj] = biaso[bcol * 128 + wc * 64 + nj * 16 + lrow];

  #pragma unroll
  for (int mi = 0; mi < 4; ++mi) {
    #pragma unroll
    for (int r = 0; r < 4; ++r) {
      const int gr = brow * 128 + wr * 64 + mi * 16 + lk * 4 + r;
      #pragma unroll
      for (int nj = 0; nj < 4; ++nj) {
        const int gc = bcol * 128 + wc * 64 + nj * 16 + lrow;
        out[(size_t)gr * 1024 + gc] = acc[mi][nj][r] + bcv[nj];
      }
    }
  }
}

// ---------------------------------------------------------------------------
extern "C" void kernel_launch(void* const* d_in, const int* in_sizes, int n_in,
                              void* d_out, int out_size, void* d_ws, size_t ws_size,
                              hipStream_t stream) {
  (void)in_sizes; (void)n_in; (void)out_size; (void)ws_size;
  const float* x   = (const float*)d_in[0];
  const float* qw  = (const float*)d_in[1];
  const float* qb  = (const float*)d_in[2];
  const float* qla = (const float*)d_in[3];
  const float* qlb = (const float*)d_in[4];
  const float* kw  = (const float*)d_in[5];
  const float* kb  = (const float*)d_in[6];
  const float* kla = (const float*)d_in[7];
  const float* klb = (const float*)d_in[8];
  const float* vw  = (const float*)d_in[9];
  const float* vb  = (const float*)d_in[10];
  const float* vla = (const float*)d_in[11];
  const float* vlb = (const float*)d_in[12];
  const float* ow  = (const float*)d_in[13];
  const float* ob  = (const float*)d_in[14];
  const float* ola = (const float*)d_in[15];
  const float* olb = (const float*)d_in[16];

  short* xb   = (short*)d_ws;                         // 4096*1024 bf16 (reused as ctx)
  short* wb   = xb + (size_t)4096 * 1024;             // 4*1024*1024 bf16
  short* qbuf = wb + (size_t)4 * 1024 * 1024;         // 64*1024*64 each
  short* kbuf = qbuf + (size_t)4194304;
  short* vtb  = kbuf + (size_t)4194304;               // total 40 MB

  build_x<<<4096, 256, 0, stream>>>(x, xb);
  fold_w<<<dim3(1024, 4), 256, 0, stream>>>(qw, kw, vw, ow, qlb, klb, vlb, olb,
                                            qla, kla, vla, ola, wb);
  gemm_qkv<<<192, 512, 0, stream>>>(xb, wb, qb, kb, vb, qbuf, kbuf, vtb);
  attn_kernel<<<dim3(64, 8), 256, 0, stream>>>(qbuf, kbuf, vtb, xb);
  gemm_o<<<dim3(8, 32), 256, 0, stream>>>(xb, wb + (size_t)3 * 1024 * 1024, ob, (float*)d_out);
}